// Round 13
// baseline (238.716 us; speedup 1.0000x reference)
//
#include <hip/hip_runtime.h>
#include <math.h>

#define BB 8
#define NN 2048
#define DD 256
#define MTOK 16384

typedef __bf16 bf16x8 __attribute__((ext_vector_type(8)));
typedef __bf16 bf16x4 __attribute__((ext_vector_type(4)));
typedef float f32x4 __attribute__((ext_vector_type(4)));
typedef float f32x16 __attribute__((ext_vector_type(16)));

#define MFMA16(a, b, c) __builtin_amdgcn_mfma_f32_16x16x32_bf16(a, b, c, 0, 0, 0)
#define MFMA32(a, b, c) __builtin_amdgcn_mfma_f32_32x32x16_bf16(a, b, c, 0, 0, 0)

// raw barrier + compiler memory fence (no implicit vmcnt(0) drain)
#define BARX()                              \
  do {                                      \
    asm volatile("" ::: "memory");          \
    __builtin_amdgcn_s_barrier();           \
    asm volatile("" ::: "memory");          \
  } while (0)
// counted vmem wait (literal N) + scheduling fence
#define WAITVM(N)                                              \
  do {                                                         \
    asm volatile("s_waitcnt vmcnt(" #N ")" ::: "memory");      \
    __builtin_amdgcn_sched_barrier(0);                         \
  } while (0)

// ---- workspace layout (float offsets) ----
#define OFF_X16    0ull          // bf16 [16384][256]
#define OFF_N16    2097152ull    // bf16 [16384][256]
#define OFF_H16    4194304ull    // bf16 [16384][256]
#define OFF_GROW   8388608ull    // bf16 [16384][512]  ([q/16 | fs*sqrt(.5)])
#define OFF_GCOL   12582912ull   // bf16 [16384][512]  ([k    | unused hi])
#define OFF_PTE    16777216ull   // bf16 [8][288][2048] (stats rows 256..258)
#define OFF_WT     19136512ull   // bf16 weights transposed
#define OFF_STAT   19365888ull   // f32 [2][16384][6] attn half-stats
#define OFF_ENT    23625728ull
#define OFF_MONR   23642112ull
#define OFF_HUBR   23658496ull
#define OFF_MONF   23674880ull
#define OFF_HUBF   23676928ull
#define OFF_MASK   23678976ull   // 16384 bytes
#define OFF_PART   23683072ull   // f32 [64][4] reduce partials
// aliases (dead-region reuse):
#define OFF_MSGN0  OFF_N16       // bf16 [16384][256]; N16 dead after proj
#define OFF_MSGN1  OFF_H16       // bf16 [16384][256]; H16 dead after proj
#define OFF_MSG16  OFF_PTE       // bf16 [16384][256]; PTE dead after attn
#define OFF_GM16   OFF_GROW      // bf16 [16384][256]; GROW dead after attn

__device__ __forceinline__ void gl_lds16(const void* g, void* l) {
  __builtin_amdgcn_global_load_lds(
      (const __attribute__((address_space(1))) unsigned int*)g,
      (__attribute__((address_space(3))) unsigned int*)l, 16, 0, 0);
}

// --- merged setup: prep(0..4095) | wt(4096..4287) | mask(4288..4351) |
//     fill_pte(4352..4415) — all uniform-duration block ranges, no tails ---
__global__ __launch_bounds__(256) void setup_kernel(
    const float* __restrict__ x, const int* __restrict__ roles,
    const void* __restrict__ mraw,
    const float* __restrict__ gamma, const float* __restrict__ beta,
    const float* __restrict__ role_emb,
    const float* __restrict__ Wq, const float* __restrict__ Wk,
    const float* __restrict__ Ws, const float* __restrict__ Wp,
    const float* __restrict__ Wg, const float* __restrict__ Wo,
    __bf16* __restrict__ X16, __bf16* __restrict__ N16,
    __bf16* __restrict__ H16, __bf16* __restrict__ WT,
    unsigned char* __restrict__ mask8,
    float* __restrict__ monf, float* __restrict__ hubf,
    __bf16* __restrict__ PTE) {
  __shared__ float T[64][65];
  int bid = blockIdx.x;
  int tid = threadIdx.x;
  if (bid < 4096) {
    int t = bid * 4 + (tid >> 6);
    int lane = tid & 63;
    size_t off = (size_t)t * DD + lane * 4;
    float4 xv = *(const float4*)(x + off);
    float s = xv.x + xv.y + xv.z + xv.w;
    float ss = xv.x * xv.x + xv.y * xv.y + xv.z * xv.z + xv.w * xv.w;
#pragma unroll
    for (int m = 1; m < 64; m <<= 1) {
      s += __shfl_xor(s, m, 64);
      ss += __shfl_xor(ss, m, 64);
    }
    float mu = s * (1.0f / 256.0f);
    float var = ss * (1.0f / 256.0f) - mu * mu;
    float inv = rsqrtf(var + 1e-5f);
    float4 g = *(const float4*)(gamma + lane * 4);
    float4 be = *(const float4*)(beta + lane * 4);
    float nv[4];
    nv[0] = (xv.x - mu) * inv * g.x + be.x;
    nv[1] = (xv.y - mu) * inv * g.y + be.y;
    nv[2] = (xv.z - mu) * inv * g.z + be.z;
    nv[3] = (xv.w - mu) * inv * g.w + be.w;
    int role = roles[t];
    float4 rb = *(const float4*)(role_emb + (size_t)role * DD + lane * 4);
    float rbv[4] = {rb.x, rb.y, rb.z, rb.w};
    bf16x4 xo, no, ho;
    float xf[4] = {xv.x, xv.y, xv.z, xv.w};
#pragma unroll
    for (int q = 0; q < 4; ++q) {
      xo[q] = (__bf16)xf[q];
      no[q] = (__bf16)nv[q];
      ho[q] = (__bf16)(nv[q] + rbv[q]);
    }
    *(bf16x4*)&X16[off] = xo;
    *(bf16x4*)&N16[off] = no;
    *(bf16x4*)&H16[off] = ho;
  } else if (bid < 4288) {
    int wblk = bid - 4096;
    int z = wblk >> 5, rem = wblk & 31;
    int bx = rem & 3, by = rem >> 2;
    const float* src;
    int K;
    size_t doff;
    switch (z) {
      case 0: src = Wq; K = 256; doff = 0; break;
      case 1: src = Wk; K = 256; doff = 65536; break;
      case 2: src = Ws; K = 256; doff = 131072; break;
      case 3: src = Wp; K = 256; doff = 196608; break;
      case 4: src = Wg; K = 512; doff = 262144; break;
      default: src = Wo; K = 256; doff = 393216; break;
    }
    int k0 = by * 64;
    if (k0 >= K) return;
    int n0 = bx * 64;
#pragma unroll
    for (int p = 0; p < 16; ++p) {
      int idx = p * 256 + tid;
      int r = idx >> 6, c = idx & 63;
      T[r][c] = src[(size_t)(k0 + r) * 256 + n0 + c];
    }
    __syncthreads();
#pragma unroll
    for (int p = 0; p < 16; ++p) {
      int idx = p * 256 + tid;
      int n = idx >> 6, k = idx & 63;
      WT[doff + (size_t)(n0 + n) * K + k0 + k] = (__bf16)T[k][n];
    }
  } else if (bid < 4352) {
    int* csh = (int*)&T[0][0];
    if (tid == 0) { csh[0] = 0; csh[1] = 0; }
    __syncthreads();
    const unsigned char* raw = (const unsigned char*)mraw;
    int c0 = 0, c1 = 0;
    for (int i = tid; i < 4096; i += 256) {
      int nz = (raw[i] != 0) ? 1 : 0;
      if ((i & 3) == 0) c0 += nz; else c1 += nz;
    }
    atomicAdd(&csh[0], c0);
    atomicAdd(&csh[1], c1);
    __syncthreads();
    int k = (csh[0] == 0) ? 2 : ((csh[1] == 0) ? 0 : 1);
    int t = (bid - 4288) * 256 + tid;
    if (t < MTOK) {
      int v;
      if (k == 1)      v = (raw[t] != 0);
      else if (k == 0) v = (((const int*)mraw)[t] != 0);
      else             v = (((const float*)mraw)[t] != 0.0f);
      mask8[t] = (unsigned char)v;
    }
    if (t < NN) {
      int mon = 0, hub = 0;
#pragma unroll
      for (int b = 0; b < BB; ++b) {
        int r = roles[b * NN + t];
        mon |= (r == 2) ? 1 : 0;
        hub |= (r == 1) ? 1 : 0;
      }
      monf[t] = (float)mon;
      hubf[t] = (float)hub;
    }
  } else {
    // fill_pte: PTE stat rows 256..287 (mon/hub/ones then zeros)
    int idx = (bid - 4352) * 256 + tid;   // 16384 = b(8) x col(2048)
    int b = idx >> 11, col = idx & 2047;
    int mon = 0, hub = 0;
#pragma unroll
    for (int bb = 0; bb < BB; ++bb) {
      int r = roles[bb * NN + col];
      mon |= (r == 2) ? 1 : 0;
      hub |= (r == 1) ? 1 : 0;
    }
    size_t rbase = ((size_t)(b * 288 + 256)) * 2048 + col;
    PTE[rbase] = (__bf16)(float)mon;
    PTE[rbase + 2048] = (__bf16)(float)hub;
    PTE[rbase + 2 * 2048] = (__bf16)1.0f;
#pragma unroll
    for (int r = 3; r < 32; ++r) PTE[rbase + (size_t)r * 2048] = (__bf16)0.0f;
  }
}

// -------- fused q/k/fs/p projections (z = 0..3), K=256, tile 128x128 --------
__global__ __launch_bounds__(256, 4) void proj4_kernel(
    const __bf16* __restrict__ H16, const __bf16* __restrict__ N16,
    const __bf16* __restrict__ WT,
    const float* __restrict__ bq, const float* __restrict__ bk,
    const float* __restrict__ bs, const float* __restrict__ bp,
    const int* __restrict__ roles, const float* __restrict__ remb,
    __bf16* __restrict__ Grow, __bf16* __restrict__ Gcol,
    __bf16* __restrict__ PTE) {
  __shared__ __align__(16) unsigned char As[128 * 128];
  __shared__ __align__(16) unsigned char Bs[128 * 128];
  int z = blockIdx.z;
  const __bf16* A = (z == 3) ? N16 : H16;
  const __bf16* W = WT + (size_t)z * 65536;
  const float* bias = (z == 0) ? bq : (z == 1) ? bk : (z == 2) ? bs : bp;

  int tid = threadIdx.x;
  int w = tid >> 6, lane = tid & 63, ln15 = lane & 15, lq = lane >> 4;
  int wr = w >> 1, wc = w & 1;
  int row0 = blockIdx.y * 128, col0 = blockIdx.x * 128;
  f32x4 acc[4][4];
#pragma unroll
  for (int i = 0; i < 4; ++i)
#pragma unroll
    for (int j = 0; j < 4; ++j) acc[i][j] = (f32x4){0.f, 0.f, 0.f, 0.f};

  int lr = lane >> 3;
  int sb = ((lane & 7) * 16) ^ ((lr & 7) << 4);

  for (int kt = 0; kt < 4; ++kt) {
    __syncthreads();
#pragma unroll
    for (int i2 = 0; i2 < 4; ++i2) {
      int idx = w * 4 + i2;
      int grow = row0 + idx * 8 + lr;
      gl_lds16((const unsigned char*)A + (size_t)grow * 512 + kt * 128 + sb,
               As + idx * 1024);
    }
#pragma unroll
    for (int i2 = 0; i2 < 4; ++i2) {
      int idx = w * 4 + i2;
      int gcol = col0 + idx * 8 + lr;
      gl_lds16((const unsigned char*)W + (size_t)gcol * 512 + kt * 128 + sb,
               Bs + idx * 1024);
    }
    __syncthreads();
#pragma unroll
    for (int ks = 0; ks < 2; ++ks) {
      bf16x8 af[4], bfr[4];
#pragma unroll
      for (int i = 0; i < 4; ++i) {
        int rl = wr * 64 + i * 16 + ln15;
        int byteoff = (lq * 16 + ks * 64) ^ ((rl & 7) << 4);
        af[i] = *(const bf16x8*)(As + rl * 128 + byteoff);
      }
#pragma unroll
      for (int j = 0; j < 4; ++j) {
        int cl = wc * 64 + j * 16 + ln15;
        int byteoff = (lq * 16 + ks * 64) ^ ((cl & 7) << 4);
        bfr[j] = *(const bf16x8*)(Bs + cl * 128 + byteoff);
      }
#pragma unroll
      for (int i = 0; i < 4; ++i)
#pragma unroll
        for (int j = 0; j < 4; ++j) acc[i][j] = MFMA16(af[i], bfr[j], acc[i][j]);
    }
  }
  float bj[4];
#pragma unroll
  for (int j = 0; j < 4; ++j) bj[j] = bias[col0 + wc * 64 + j * 16 + ln15];
#pragma unroll
  for (int i = 0; i < 4; ++i) {
#pragma unroll
    for (int j = 0; j < 4; ++j) {
      int gcol = col0 + wc * 64 + j * 16 + ln15;
      int growb = row0 + wr * 64 + i * 16 + lq * 4;
      float o[4];
#pragma unroll
      for (int ri = 0; ri < 4; ++ri) o[ri] = acc[i][j][ri] + bj[j];
      if (z == 0) {
#pragma unroll
        for (int ri = 0; ri < 4; ++ri)
          Grow[(size_t)(growb + ri) * 512 + gcol] = (__bf16)(o[ri] * 0.0625f);
      } else if (z == 1) {
#pragma unroll
        for (int ri = 0; ri < 4; ++ri)
          Gcol[(size_t)(growb + ri) * 512 + gcol] = (__bf16)o[ri];
      } else if (z == 2) {
#pragma unroll
        for (int ri = 0; ri < 4; ++ri) {
          float oo = o[ri] + remb[(size_t)roles[growb + ri] * 256 + gcol];
          Grow[(size_t)(growb + ri) * 512 + 256 + gcol] =
              (__bf16)(oo * 0.70710678118f);
        }
      } else {
        bf16x4 v;
#pragma unroll
        for (int ri = 0; ri < 4; ++ri) v[ri] = (__bf16)o[ri];
        int b = growb >> 11, tok = growb & 2047;
        *(bf16x4*)&PTE[((size_t)(b * 288 + gcol)) * 2048 + tok] = v;
      }
    }
  }
}

// ---------------- MFMA flash attention v9: 32x32x16 MFMA ----------------
// grid 256 (id = qblock*16 + half*8 + batch; XCD==batch). 4 waves x 32 q.
// Half the LDS reads per FLOP vs 16x16x32. Full double-buffer (136KB LDS,
// 1 block/CU), 2 barriers + one counted WAITVM(17) per chunk (17 loads
// always in flight). Swapped S: D[kv][q]; lane-local softmax (16 vals +
// one shfl_xor(32)); PV A-fragment via cvt_pk_bf16 + permlane32_swap (T12).
__global__ __launch_bounds__(256, 1) void attn_kernel(
    const __bf16* __restrict__ Grow, const __bf16* __restrict__ Gcol,
    const __bf16* __restrict__ PTE, const unsigned char* __restrict__ mask8,
    __bf16* __restrict__ msgn0, __bf16* __restrict__ msgn1,
    float* __restrict__ statP) {
  __shared__ __align__(16) unsigned char GcLo[2][16384];  // [32 kv][512B] swz
  __shared__ __align__(16) unsigned char GcHi[2][16384];  // [32 kv][512B] swz
  __shared__ __align__(16) unsigned char PtS[2][36864];   // [288 d][128B] swz

  int tid = threadIdx.x;
  int w = tid >> 6;
  int l = tid & 63, l31 = l & 31, hi = l >> 5;
  int id = blockIdx.x;
  int b = id & 7;
  int half = (id >> 3) & 1;
  int r0 = (id >> 4) * 128;
  int q0w = r0 + w * 32;
  size_t base = (size_t)b * NN;
  __bf16* msgn = half ? msgn1 : msgn0;
  float* statB = statP + (size_t)half * MTOK * 6;

  const unsigned char* gbaseK =
      (const unsigned char*)Gcol + (base + half * 1024) * 1024;
  const unsigned char* gbaseF =
      (const unsigned char*)Grow + (base + half * 1024) * 1024;
  const unsigned char* pbase =
      (const unsigned char*)PTE + (size_t)b * 288 * 4096 + half * 2048;

  // A-side q fragments: lane l31 = q-row, hi selects k-half of each 16-k step
  bf16x8 Af[32];
  {
    const __bf16* gr = Grow + (base + q0w + l31) * 512 + hi * 8;
#pragma unroll
    for (int ks = 0; ks < 32; ++ks) Af[ks] = *(const bf16x8*)(gr + ks * 16);
  }
  WAITVM(0);   // Af landed; vmcnt ledger now exact

  float m = -1e30f, T = 0.f;   // softmax state for q-row l31 (replicated hi/lo)
  f32x16 macc[9];
#pragma unroll
  for (int t = 0; t < 9; ++t)
#pragma unroll
    for (int r = 0; r < 16; ++r) macc[t][r] = 0.f;

  int gsw = (l31 & 7) << 4;   // read-side swizzle (row = l31 mod 8)

  auto STAGE = [&](int ch, int bufi) {
#pragma unroll
    for (int i = 0; i < 4; ++i) {          // GcLo: k 0..255 from Gcol
      int rp = w * 8 + 2 * i;
      int rl = rp + hi;
      gl_lds16(gbaseK + (size_t)(ch * 32 + rl) * 1024 +
                   ((l31 * 16) ^ ((rl & 7) << 4)),
               &GcLo[bufi][rp * 512]);
    }
#pragma unroll
    for (int i = 0; i < 4; ++i) {          // GcHi: fs (k 256..511) from Grow
      int rp = w * 8 + 2 * i;
      int rl = rp + hi;
      gl_lds16(gbaseF + (size_t)(ch * 32 + rl) * 1024 + 512 +
                   ((l31 * 16) ^ ((rl & 7) << 4)),
               &GcHi[bufi][rp * 512]);
    }
#pragma unroll
    for (int i = 0; i < 9; ++i) {          // Pt: 288 d-rows, 128B LDS rows
      int R = w * 72 + i * 8;
      int rl = R + (l >> 3);
      int c = (((l & 7) * 16) ^ ((rl & 7) << 4)) & 63;  // dup for pad slots
      gl_lds16(pbase + (size_t)rl * 4096 + ch * 64 + c,
               &PtS[bufi][R * 128]);
    }
  };

  STAGE(0, 0);   // 17 in flight

  for (int ch = 0; ch < 32; ++ch) {
    int buf = ch & 1;
    STAGE(ch + 1, buf ^ 1);   // 34 in flight
    WAITVM(17);               // ch's 17 landed; ch+1's stay in flight
    BARX();

    // ---- S: D[kv][q] over K=512 ----
    f32x16 sa;
#pragma unroll
    for (int r = 0; r < 16; ++r) sa[r] = 0.f;
    __builtin_amdgcn_s_setprio(1);
#pragma unroll
    for (int ks = 0; ks < 16; ++ks) {
      bf16x8 a = *(const bf16x8*)&GcLo[buf][l31 * 512 +
                                           ((ks * 32 + hi * 16) ^ gsw)];
      sa = MFMA32(a, Af[ks], sa);
    }
#pragma unroll
    for (int ks = 16; ks < 32; ++ks) {
      bf16x8 a = *(const bf16x8*)&GcHi[buf][l31 * 512 +
                                            (((ks - 16) * 32 + hi * 16) ^ gsw)];
      sa = MFMA32(a, Af[ks], sa);
    }
    __builtin_amdgcn_s_setprio(0);

    // lane holds S[kv_r][q=l31], kv_r = (r&3)+8*(r>>2)+4*hi (+ch*32+half*1024)
    const unsigned long long* mp = (const unsigned long long*)(
        mask8 + base + half * 1024 + (size_t)ch * 32);
    unsigned sel[4];
#pragma unroll
    for (int j = 0; j < 4; ++j) sel[j] = (unsigned)(mp[j] >> (hi * 32));

    float sv[16];
    int vld[16];
#pragma unroll
    for (int r = 0; r < 16; ++r) {
      sv[r] = sa[r];
      vld[r] = (sel[r >> 2] >> (8 * (r & 3))) & 0xff;
    }
    float mt = -1e30f;
#pragma unroll
    for (int r = 0; r < 16; ++r) mt = fmaxf(mt, vld[r] ? sv[r] : -1e30f);
    mt = fmaxf(mt, __shfl_xor(mt, 32));
    float mnew = fmaxf(m, mt);
    if (__any(mnew > m + 8.0f)) {    // defer-max (T13)
      float ci = __expf(m - mnew);
      float cir[16];
#pragma unroll
      for (int r = 0; r < 16; ++r)
        cir[r] = __shfl(ci, (r & 3) + 8 * (r >> 2) + 4 * hi);
#pragma unroll
      for (int t = 0; t < 9; ++t)
#pragma unroll
        for (int r = 0; r < 16; ++r) macc[t][r] *= cir[r];
      T *= ci;
      m = mnew;
    }
    float e[16], tl = 0.f;
#pragma unroll
    for (int r = 0; r < 16; ++r) {
      float ee = vld[r] ? __expf(sv[r] - m) : 0.f;
      e[r] = ee;
      tl += ee * sv[r];
    }
    tl += __shfl_xor(tl, 32);
    T += tl;

    // ---- P A-fragment assembly: cvt_pk + permlane32_swap (T12) ----
    unsigned wj[8];
#pragma unroll
    for (int j = 0; j < 8; ++j)
      asm("v_cvt_pk_bf16_f32 %0, %1, %2"
          : "=v"(wj[j]) : "v"(e[2 * j]), "v"(e[2 * j + 1]));
    asm volatile("v_permlane32_swap_b32 %0, %1" : "+v"(wj[0]), "+v"(wj[2]));
    asm volatile("v_permlane32_swap_b32 %0, %1" : "+v"(wj[1]), "+v"(wj[3]));
    asm volatile("v_permlane32_swap_b32 %0, %1" : "+v"(wj[4]), "+v"(wj[6]));
    asm volatile("v_permlane32_swap_b32 %0, %1" : "+v"(wj[5]), "+v"(wj[7]));
    union { unsigned u[4]; bf16x8 v; } ue0, ue1;
    ue0.u[0] = wj[0]; ue0.u[1] = wj[1]; ue0.u[2] = wj[2]; ue0.u[3] = wj[3];
    ue1.u[0] = wj[4]; ue1.u[1] = wj[5]; ue1.u[2] = wj[6]; ue1.u[3] = wj[7];
    bf16x8 ef0 = ue0.v, ef1 = ue1.v;

    // ---- PV: 9 d-tiles x 2 kv-halves ----
    __builtin_amdgcn_s_setprio(1);
#pragma unroll
    for (int t = 0; t < 9; ++t) {
      const unsigned char* pb = &PtS[buf][(t * 32 + l31) * 128];
      bf16x8 b0 = *(const bf16x8*)(pb + ((hi * 16) ^ gsw));
      macc[t] = MFMA32(ef0, b0, macc[t]);
      bf16x8 b1 = *(const bf16x8*)(pb + ((32 + hi * 16) ^ gsw));
      macc[t] = MFMA32(ef1, b1, macc[t]);
    }
    __builtin_amdgcn_s_setprio(0);
    BARX();   // all waves done with buf; next iter's STAGE targets it
  }
  WAITVM(0);   // drain trailing (unused) prefetch

  // ---- finalize: macc rows q_r = (r&3)+8*(r>>2)+4*hi ----
#pragma unroll
  for (int r = 0; r < 16; ++r) {
    int qr = (r & 3) + 8 * (r >> 2) + 4 * hi;
    size_t row = base + q0w + qr;
    float Z  = __shfl(macc[8][r], (l & 32) + 2);
    float Tm = __shfl(macc[8][r], (l & 32) + 0);
    float Th = __shfl(macc[8][r], (l & 32) + 1);
    float invZ = (Z > 0.f) ? (1.0f / Z) : 0.f;
#pragma unroll
    for (int t = 0; t < 8; ++t)
      msgn[row * 256 + t * 32 + l31] = (__bf16)(macc[t][r] * invZ);
    float mr = __shfl(m, qr);
    float Tr = __shfl(T, qr);
    if (l31 == 0) {
      float* stt = statB + row * 6;
      stt[0] = mr; stt[1] = Tr; stt[2] = Z; stt[3] = Tm; stt[4] = Th;
    }
  }
}

// ---------------- merge halves (weighted bf16 partials) ----------------
__global__ __launch_bounds__(256) void merge_kernel(
    const __bf16* __restrict__ msgn0, const __bf16* __restrict__ msgn1,
    const float* __restrict__ statP, const unsigned char* __restrict__ mask8,
    __bf16* __restrict__ MSG16, float* __restrict__ entr,
    float* __restrict__ monr, float* __restrict__ hubr) {
  int row = blockIdx.x * 4 + (threadIdx.x >> 6);
  int lane = threadIdx.x & 63;
  const float* s0 = statP + (size_t)row * 6;
  const float* s1 = statP + (size_t)(MTOK + row) * 6;
  float m0 = s0[0], T0 = s0[1], Z0 = s0[2], Tm0 = s0[3], Th0 = s0[4];
  float m1 = s1[0], T1 = s1[1], Z1 = s1[2], Tm1 = s1[3], Th1 = s1[4];
  int valid = mask8[row] != 0;
  float mm = fmaxf(m0, m1);
  float c0 = __expf(m0 - mm), c1 = __expf(m1 - mm);
  float w0 = c0 * Z0, w1 = c1 * Z1;
  float Z = w0 + w1;
  int ok = valid && (Z > 0.f);
  float invZ = ok ? (1.0f / Z) : 0.0f;
  float rw0 = w0 * invZ, rw1 = w1 * invZ;
  bf16x4 p0 = *(const bf16x4*)(msgn0 + (size_t)row * 256 + lane * 4);
  bf16x4 p1 = *(const bf16x4*)(msgn1 + (size_t)row * 256 + lane * 4);
  bf16x4 o;
#pragma unroll
  for (int q = 0; q < 4; ++q)
    o[q] = (__bf16)(rw0 * (float)p0[q] + rw1 * (float)p1[q]);
  *(bf16x4*)&MSG16[(size_t)row * 256 + lane * 4] = o;
  if (lane == 0) {
    float T = c0 * T0 + c1 * T1;
    float Tm = c0 * Tm0 + c1 * Tm1;
    float Th = c0 * Th0 + c1 * Th1;
    entr[row] = ok ? (__logf(Z) + mm - T * invZ) : 0.0f;
    monr[row] = ok ? (Tm * invZ) : 0.0f;
    hubr[row] = ok ? (Th * invZ) : 0.0f;
  }
}

// ---------------- MFMA GEMM (gate / out), tile 128x64 ----------------
template <int K, int MODE>
__global__ __launch_bounds__(256) void gemmb_kernel(
    const __bf16* __restrict__ A0, const __bf16* __restrict__ A1,
    const __bf16* __restrict__ WT, const float* __restrict__ bias,
    const float* __restrict__ xf, const __bf16* __restrict__ msg16,
    void* __restrict__ dst0) {
  __shared__ __align__(16) unsigned char As[128 * 128];
  __shared__ __align__(16) unsigned char Bs[64 * 128];
  int tid = threadIdx.x;
  int w = tid >> 6, lane = tid & 63, ln15 = lane & 15, lq = lane >> 4;
  int wr = w >> 1, wc = w & 1;
  int row0 = blockIdx.y * 128, col0 = blockIdx.x * 64;
  f32x4 acc[4][2];
#pragma unroll
  for (int i = 0; i < 4; ++i)
#pragma unroll
    for (int j = 0; j < 2; ++j) acc[i][j] = (f32x4){0.f, 0.f, 0.f, 0.f};

  int lr = lane >> 3;
  int sb = ((lane & 7) * 16) ^ ((lr & 7) << 4);

  for (int kt = 0; kt < K / 64; ++kt) {
    const __bf16* Ab = A0;
    int ktl = kt;
    if (K == 512 && kt >= 4) { Ab = A1; ktl = kt - 4; }
    __syncthreads();
#pragma unroll
    for (int i2 = 0; i2 < 4; ++i2) {
      int idx = w * 4 + i2;
      int grow = row0 + idx * 8 + lr;
      gl_lds16((const unsigned char*)Ab + (size_t)grow * 512 + ktl * 128 + sb,
               As + idx * 1024);
    }
#pragma unroll
    for (int i2 = 0; i2 < 2; ++i2) {
      int idx = w * 2 + i2;
      int gcol = col0 + idx * 8 + lr;
      gl_lds16((const unsigned char*)WT + (size_t)gcol * (K * 2) + kt * 128 + sb,
               Bs + idx * 1024);
    }
    __syncthreads();
#pragma unroll
    for (int ks = 0; ks < 2; ++ks) {
      bf16x8 af[4], bfr[2];
#pragma unroll
      for (int i = 0; i < 4; ++i) {
        int rl = wr * 64 + i * 16 + ln15;
        int byteoff = (lq * 16 + ks * 64) ^ ((rl & 7) << 4);
        af[i] = *(const bf16x8*)(As + rl * 128 + byteoff);
      }
#pragma unroll
      for (int j = 0; j < 2; ++j) {
        int cl = wc * 32 + j * 16 + ln15;
        int byteoff = (lq * 16 + ks * 64) ^ ((cl & 7) << 4);
        bfr[j] = *(const bf16x8*)(Bs + cl * 128 + byteoff);
      }
#pragma unroll
      for (int i = 0; i < 4; ++i)
#pragma unroll
        for (int j = 0; j < 2; ++j) acc[i][j] = MFMA16(af[i], bfr[j], acc[i][j]);
    }
  }
  float bj[2];
#pragma unroll
  for (int j = 0; j < 2; ++j) bj[j] = bias[col0 + wc * 32 + j * 16 + ln15];
#pragma unroll
  for (int i = 0; i < 4; ++i) {
#pragma unroll
    for (int ri = 0; ri < 4; ++ri) {
      int grow = row0 + wr * 64 + i * 16 + lq * 4 + ri;
#pragma unroll
      for (int j = 0; j < 2; ++j) {
        int gcol = col0 + wc * 32 + j * 16 + ln15;
        float o = acc[i][j][ri] + bj[j];
        if (MODE == 4) {
          float sg = 1.0f / (1.0f + __expf(-o));
          float mv = (float)msg16[(size_t)grow * 256 + gcol];
          ((__bf16*)dst0)[(size_t)grow * 256 + gcol] = (__bf16)(sg * mv);
        } else {
          ((float*)dst0)[(size_t)grow * 256 + gcol] =
              o + xf[(size_t)grow * 256 + gcol];
        }
      }
    }
  }
}

// ---------------- two-stage scalar reduction ----------------
__device__ __forceinline__ float block_sum(float v, float* sh) {
  __syncthreads();
  sh[threadIdx.x] = v;
  __syncthreads();
  for (int s = 128; s > 0; s >>= 1) {
    if ((int)threadIdx.x < s) sh[threadIdx.x] += sh[threadIdx.x + s];
    __syncthreads();
  }
  return sh[0];
}

__global__ __launch_bounds__(256) void reduce1_kernel(
    const float* __restrict__ entr, const float* __restrict__ monr,
    const float* __restrict__ hubr, float* __restrict__ partial) {
  __shared__ float sh[256];
  int t = blockIdx.x * 256 + threadIdx.x;
  float es = entr[t], ms = monr[t], hs = hubr[t];
  float e = block_sum(es, sh);
  float mo = block_sum(ms, sh);
  float hu = block_sum(hs, sh);
  if (threadIdx.x == 0) {
    partial[blockIdx.x * 4 + 0] = e;
    partial[blockIdx.x * 4 + 1] = mo;
    partial[blockIdx.x * 4 + 2] = hu;
  }
}

__global__ __launch_bounds__(256) void reduce2_kernel(
    const float* __restrict__ partial, const float* __restrict__ monf,
    const float* __restrict__ hubf, float* __restrict__ out3) {
  __shared__ float sh[256];
  float es = 0.f, ms = 0.f, hs = 0.f, cmf = 0.f, chf = 0.f;
  if (threadIdx.x < 64) {
    es = partial[threadIdx.x * 4 + 0];
    ms = partial[threadIdx.x * 4 + 1];
    hs = partial[threadIdx.x * 4 + 2];
  }
  for (int j = threadIdx.x; j < NN; j += 256) { cmf += monf[j]; chf += hubf[j]; }
  float esum = block_sum(es, sh);
  float msum = block_sum(ms, sh);
  float hsum = block_sum(hs, sh);
  float cmsum = block_sum(cmf, sh);
  float chsum = block_sum(chf, sh);
  if (threadIdx.x == 0) {
    out3[0] = esum / 16384.0f;
    out3[1] = (cmsum > 0.f) ? (msum / (cmsum * 16384.0f)) : 0.0f;
    out3[2] = (chsum > 0.f) ? (hsum / (chsum * 16384.0f)) : 0.0f;
  }
}

extern "C" void kernel_launch(void* const* d_in, const int* in_sizes, int n_in,
                              void* d_out, int out_size, void* d_ws, size_t ws_size,
                              hipStream_t stream) {
  const float* x = (const float*)d_in[0];
  const int* roles = (const int*)d_in[1];
  const void* mraw = d_in[2];
  const float* gamma = (const float*)d_in[3];
  const float* beta = (const float*)d_in[4];
  const float* remb = (const float*)d_in[5];
  const float* Wq = (const float*)d_in[6];
  const float* bq = (const float*)d_in[7];
  const float* Wk = (const float*)d_in[8];
  const float* bk = (const float*)d_in[9];
  const float* Ws = (const float*)d_in[10];
  const float* bs = (const float*)d_in[11];
  const float* Wp = (const float*)d_in[12];
  const float* bp = (const float*)d_in[13];
  const float* Wo = (const float*)d_in[14];
  const float* bo = (const float*)d_in[15];
  const float* Wg = (const float*)d_in[16];
  const float* bg = (const float*)d_in[17];

  float* ws = (float*)d_ws;
  __bf16* X16 = (__bf16*)(ws + OFF_X16);
  __bf16* N16 = (__bf16*)(ws + OFF_N16);
  __bf16* H16 = (__bf16*)(ws + OFF_H16);
  __bf16* Grow = (__bf16*)(ws + OFF_GROW);
  __bf16* Gcol = (__bf16*)(ws + OFF_GCOL);
  __bf16* PTE = (__bf16*)(ws + OFF_PTE);
  __bf16* WT = (__bf16*)(ws + OFF_WT);
  float* statP = ws + OFF_STAT;
  __bf16* msgn0 = (__bf16*)(ws + OFF_MSGN0);
  __bf16* msgn1 = (__bf16*)(ws + OFF_MSGN1);
  float* partial = ws + OFF_PART;
  __bf16* MSG16 = (__bf16*)(ws + OFF_MSG16);
  __bf16* GM16 = (__bf16*)(ws + OFF_GM16);
  float* entr = ws + OFF_ENT;
  float* monr = ws + OFF_MONR;
  float* hubr = ws + OFF_HUBR;
  float* monfp = ws + OFF_MONF;
  float* hubfp = ws + OFF_HUBF;
  unsigned char* mask8 = (unsigned char*)(ws + OFF_MASK);
  float* out = (float*)d_out;

  __bf16* WTg = WT + 262144;
  __bf16* WTo = WT + 393216;

  setup_kernel<<<4416, 256, 0, stream>>>(x, roles, mraw, gamma, beta, remb,
                                         Wq, Wk, Ws, Wp, Wg, Wo,
                                         X16, N16, H16, WT, mask8, monfp,
                                         hubfp, PTE);
  proj4_kernel<<<dim3(2, 128, 4), 256, 0, stream>>>(
      H16, N16, WT, bq, bk, bs, bp, roles, remb, Grow, Gcol, PTE);
  attn_kernel<<<256, 256, 0, stream>>>(Grow, Gcol, PTE, mask8, msgn0, msgn1,
                                       statP);
  merge_kernel<<<4096, 256, 0, stream>>>(msgn0, msgn1, statP, mask8, MSG16,
                                         entr, monr, hubr);
  dim3 gg(4, 128);
  gemmb_kernel<512, 4><<<gg, 256, 0, stream>>>(X16, MSG16, WTg, bg, nullptr,
                                               MSG16, GM16);
  gemmb_kernel<256, 5><<<gg, 256, 0, stream>>>(GM16, nullptr, WTo, bo, x,
                                               nullptr, out);
  reduce1_kernel<<<64, 256, 0, stream>>>(entr, monr, hubr, partial);
  reduce2_kernel<<<1, 256, 0, stream>>>(partial, monfp, hubfp, out + 4194304);
}

// Round 14
// 164.222 us; speedup vs baseline: 1.4536x; 1.4536x over previous
//
#include <hip/hip_runtime.h>
#include <math.h>

#define BB 8
#define NN 2048
#define DD 256
#define MTOK 16384

typedef __bf16 bf16x8 __attribute__((ext_vector_type(8)));
typedef __bf16 bf16x4 __attribute__((ext_vector_type(4)));
typedef float f32x4 __attribute__((ext_vector_type(4)));

#define MFMA16(a, b, c) __builtin_amdgcn_mfma_f32_16x16x32_bf16(a, b, c, 0, 0, 0)

// raw barrier + compiler memory fence (no implicit vmcnt(0) drain)
#define BARX()                              \
  do {                                      \
    asm volatile("" ::: "memory");          \
    __builtin_amdgcn_s_barrier();           \
    asm volatile("" ::: "memory");          \
  } while (0)
// counted vmem wait (literal N) + scheduling fence
#define WAITVM(N)                                              \
  do {                                                         \
    asm volatile("s_waitcnt vmcnt(" #N ")" ::: "memory");      \
    __builtin_amdgcn_sched_barrier(0);                         \
  } while (0)

// ---- workspace layout (float offsets) ----
#define OFF_X16    0ull          // bf16 [16384][256]
#define OFF_N16    2097152ull    // bf16 [16384][256]
#define OFF_H16    4194304ull    // bf16 [16384][256]
#define OFF_GROW   8388608ull    // bf16 [16384][512]  ([q/16 | fs*sqrt(.5)])
#define OFF_GCOL   12582912ull   // bf16 [16384][512]  ([k    | unused hi])
#define OFF_PTE    16777216ull   // bf16 [8][272][2048]
#define OFF_WT     19005440ull   // bf16 weights transposed
#define OFF_STAT   19234816ull   // f32 [2][16384][6] attn half-stats
#define OFF_ENT    23625728ull
#define OFF_MONR   23642112ull
#define OFF_HUBR   23658496ull
#define OFF_MONF   23674880ull
#define OFF_HUBF   23676928ull
#define OFF_MASK   23678976ull   // 16384 bytes
#define OFF_PART   23683072ull   // f32 [64][4] reduce partials
// aliases (dead-region reuse):
#define OFF_MSGN0  OFF_N16       // bf16 [16384][256]; N16 dead after proj
#define OFF_MSGN1  OFF_H16       // bf16 [16384][256]; H16 dead after proj
#define OFF_MSG16  OFF_PTE       // bf16 [16384][256]; PTE dead after attn
#define OFF_GM16   OFF_GROW      // bf16 [16384][256]; GROW dead after attn

__device__ __forceinline__ void gl_lds16(const void* g, void* l) {
  __builtin_amdgcn_global_load_lds(
      (const __attribute__((address_space(1))) unsigned int*)g,
      (__attribute__((address_space(3))) unsigned int*)l, 16, 0, 0);
}

// --- merged setup: prep(0..4095) | wt(4096..4287) | mask(4288..4351) |
//     fill_pte(4352..4415) — all uniform-duration block ranges, no tails ---
__global__ __launch_bounds__(256) void setup_kernel(
    const float* __restrict__ x, const int* __restrict__ roles,
    const void* __restrict__ mraw,
    const float* __restrict__ gamma, const float* __restrict__ beta,
    const float* __restrict__ role_emb,
    const float* __restrict__ Wq, const float* __restrict__ Wk,
    const float* __restrict__ Ws, const float* __restrict__ Wp,
    const float* __restrict__ Wg, const float* __restrict__ Wo,
    __bf16* __restrict__ X16, __bf16* __restrict__ N16,
    __bf16* __restrict__ H16, __bf16* __restrict__ WT,
    unsigned char* __restrict__ mask8,
    float* __restrict__ monf, float* __restrict__ hubf,
    __bf16* __restrict__ PTE) {
  __shared__ float T[64][65];
  int bid = blockIdx.x;
  int tid = threadIdx.x;
  if (bid < 4096) {
    int t = bid * 4 + (tid >> 6);
    int lane = tid & 63;
    size_t off = (size_t)t * DD + lane * 4;
    float4 xv = *(const float4*)(x + off);
    float s = xv.x + xv.y + xv.z + xv.w;
    float ss = xv.x * xv.x + xv.y * xv.y + xv.z * xv.z + xv.w * xv.w;
#pragma unroll
    for (int m = 1; m < 64; m <<= 1) {
      s += __shfl_xor(s, m, 64);
      ss += __shfl_xor(ss, m, 64);
    }
    float mu = s * (1.0f / 256.0f);
    float var = ss * (1.0f / 256.0f) - mu * mu;
    float inv = rsqrtf(var + 1e-5f);
    float4 g = *(const float4*)(gamma + lane * 4);
    float4 be = *(const float4*)(beta + lane * 4);
    float nv[4];
    nv[0] = (xv.x - mu) * inv * g.x + be.x;
    nv[1] = (xv.y - mu) * inv * g.y + be.y;
    nv[2] = (xv.z - mu) * inv * g.z + be.z;
    nv[3] = (xv.w - mu) * inv * g.w + be.w;
    int role = roles[t];
    float4 rb = *(const float4*)(role_emb + (size_t)role * DD + lane * 4);
    float rbv[4] = {rb.x, rb.y, rb.z, rb.w};
    bf16x4 xo, no, ho;
    float xf[4] = {xv.x, xv.y, xv.z, xv.w};
#pragma unroll
    for (int q = 0; q < 4; ++q) {
      xo[q] = (__bf16)xf[q];
      no[q] = (__bf16)nv[q];
      ho[q] = (__bf16)(nv[q] + rbv[q]);
    }
    *(bf16x4*)&X16[off] = xo;
    *(bf16x4*)&N16[off] = no;
    *(bf16x4*)&H16[off] = ho;
  } else if (bid < 4288) {
    int wblk = bid - 4096;
    int z = wblk >> 5, rem = wblk & 31;
    int bx = rem & 3, by = rem >> 2;
    const float* src;
    int K;
    size_t doff;
    switch (z) {
      case 0: src = Wq; K = 256; doff = 0; break;
      case 1: src = Wk; K = 256; doff = 65536; break;
      case 2: src = Ws; K = 256; doff = 131072; break;
      case 3: src = Wp; K = 256; doff = 196608; break;
      case 4: src = Wg; K = 512; doff = 262144; break;
      default: src = Wo; K = 256; doff = 393216; break;
    }
    int k0 = by * 64;
    if (k0 >= K) return;
    int n0 = bx * 64;
#pragma unroll
    for (int p = 0; p < 16; ++p) {
      int idx = p * 256 + tid;
      int r = idx >> 6, c = idx & 63;
      T[r][c] = src[(size_t)(k0 + r) * 256 + n0 + c];
    }
    __syncthreads();
#pragma unroll
    for (int p = 0; p < 16; ++p) {
      int idx = p * 256 + tid;
      int n = idx >> 6, k = idx & 63;
      WT[doff + (size_t)(n0 + n) * K + k0 + k] = (__bf16)T[k][n];
    }
  } else if (bid < 4352) {
    int* csh = (int*)&T[0][0];
    if (tid == 0) { csh[0] = 0; csh[1] = 0; }
    __syncthreads();
    const unsigned char* raw = (const unsigned char*)mraw;
    int c0 = 0, c1 = 0;
    for (int i = tid; i < 4096; i += 256) {
      int nz = (raw[i] != 0) ? 1 : 0;
      if ((i & 3) == 0) c0 += nz; else c1 += nz;
    }
    atomicAdd(&csh[0], c0);
    atomicAdd(&csh[1], c1);
    __syncthreads();
    int k = (csh[0] == 0) ? 2 : ((csh[1] == 0) ? 0 : 1);
    int t = (bid - 4288) * 256 + tid;
    if (t < MTOK) {
      int v;
      if (k == 1)      v = (raw[t] != 0);
      else if (k == 0) v = (((const int*)mraw)[t] != 0);
      else             v = (((const float*)mraw)[t] != 0.0f);
      mask8[t] = (unsigned char)v;
    }
    if (t < NN) {
      int mon = 0, hub = 0;
#pragma unroll
      for (int b = 0; b < BB; ++b) {
        int r = roles[b * NN + t];
        mon |= (r == 2) ? 1 : 0;
        hub |= (r == 1) ? 1 : 0;
      }
      monf[t] = (float)mon;
      hubf[t] = (float)hub;
    }
  } else {
    // fill_pte: PTE stat rows 256..271 (mon/hub from roles, uniform blocks)
    int idx = (bid - 4352) * 256 + tid;   // 16384 = b(8) x col(2048)
    int b = idx >> 11, col = idx & 2047;
    int mon = 0, hub = 0;
#pragma unroll
    for (int bb = 0; bb < BB; ++bb) {
      int r = roles[bb * NN + col];
      mon |= (r == 2) ? 1 : 0;
      hub |= (r == 1) ? 1 : 0;
    }
    size_t rbase = ((size_t)(b * 272 + 256)) * 2048 + col;
    PTE[rbase] = (__bf16)(float)mon;
    PTE[rbase + 2048] = (__bf16)(float)hub;
    PTE[rbase + 2 * 2048] = (__bf16)1.0f;
#pragma unroll
    for (int r = 3; r < 16; ++r) PTE[rbase + (size_t)r * 2048] = (__bf16)0.0f;
  }
}

// -------- fused q/k/fs/p projections (z = 0..3), K=256, tile 128x128 --------
// fs (z==2) stored ONCE in Grow+256 (Gcol hi-half unused).
__global__ __launch_bounds__(256, 4) void proj4_kernel(
    const __bf16* __restrict__ H16, const __bf16* __restrict__ N16,
    const __bf16* __restrict__ WT,
    const float* __restrict__ bq, const float* __restrict__ bk,
    const float* __restrict__ bs, const float* __restrict__ bp,
    const int* __restrict__ roles, const float* __restrict__ remb,
    __bf16* __restrict__ Grow, __bf16* __restrict__ Gcol,
    __bf16* __restrict__ PTE) {
  __shared__ __align__(16) unsigned char As[128 * 128];
  __shared__ __align__(16) unsigned char Bs[128 * 128];
  int z = blockIdx.z;
  const __bf16* A = (z == 3) ? N16 : H16;
  const __bf16* W = WT + (size_t)z * 65536;
  const float* bias = (z == 0) ? bq : (z == 1) ? bk : (z == 2) ? bs : bp;

  int tid = threadIdx.x;
  int w = tid >> 6, lane = tid & 63, ln15 = lane & 15, lq = lane >> 4;
  int wr = w >> 1, wc = w & 1;
  int row0 = blockIdx.y * 128, col0 = blockIdx.x * 128;
  f32x4 acc[4][4];
#pragma unroll
  for (int i = 0; i < 4; ++i)
#pragma unroll
    for (int j = 0; j < 4; ++j) acc[i][j] = (f32x4){0.f, 0.f, 0.f, 0.f};

  int lr = lane >> 3;
  int sb = ((lane & 7) * 16) ^ ((lr & 7) << 4);

  for (int kt = 0; kt < 4; ++kt) {
    __syncthreads();
#pragma unroll
    for (int i2 = 0; i2 < 4; ++i2) {
      int idx = w * 4 + i2;
      int grow = row0 + idx * 8 + lr;
      gl_lds16((const unsigned char*)A + (size_t)grow * 512 + kt * 128 + sb,
               As + idx * 1024);
    }
#pragma unroll
    for (int i2 = 0; i2 < 4; ++i2) {
      int idx = w * 4 + i2;
      int gcol = col0 + idx * 8 + lr;
      gl_lds16((const unsigned char*)W + (size_t)gcol * 512 + kt * 128 + sb,
               Bs + idx * 1024);
    }
    __syncthreads();
#pragma unroll
    for (int ks = 0; ks < 2; ++ks) {
      bf16x8 af[4], bfr[4];
#pragma unroll
      for (int i = 0; i < 4; ++i) {
        int rl = wr * 64 + i * 16 + ln15;
        int byteoff = (lq * 16 + ks * 64) ^ ((rl & 7) << 4);
        af[i] = *(const bf16x8*)(As + rl * 128 + byteoff);
      }
#pragma unroll
      for (int j = 0; j < 4; ++j) {
        int cl = wc * 64 + j * 16 + ln15;
        int byteoff = (lq * 16 + ks * 64) ^ ((cl & 7) << 4);
        bfr[j] = *(const bf16x8*)(Bs + cl * 128 + byteoff);
      }
#pragma unroll
      for (int i = 0; i < 4; ++i)
#pragma unroll
        for (int j = 0; j < 4; ++j) acc[i][j] = MFMA16(af[i], bfr[j], acc[i][j]);
    }
  }
  float bj[4];
#pragma unroll
  for (int j = 0; j < 4; ++j) bj[j] = bias[col0 + wc * 64 + j * 16 + ln15];
#pragma unroll
  for (int i = 0; i < 4; ++i) {
#pragma unroll
    for (int j = 0; j < 4; ++j) {
      int gcol = col0 + wc * 64 + j * 16 + ln15;
      int growb = row0 + wr * 64 + i * 16 + lq * 4;
      float o[4];
#pragma unroll
      for (int ri = 0; ri < 4; ++ri) o[ri] = acc[i][j][ri] + bj[j];
      if (z == 0) {
#pragma unroll
        for (int ri = 0; ri < 4; ++ri)
          Grow[(size_t)(growb + ri) * 512 + gcol] = (__bf16)(o[ri] * 0.0625f);
      } else if (z == 1) {
#pragma unroll
        for (int ri = 0; ri < 4; ++ri)
          Gcol[(size_t)(growb + ri) * 512 + gcol] = (__bf16)o[ri];
      } else if (z == 2) {
#pragma unroll
        for (int ri = 0; ri < 4; ++ri) {
          float oo = o[ri] + remb[(size_t)roles[growb + ri] * 256 + gcol];
          Grow[(size_t)(growb + ri) * 512 + 256 + gcol] =
              (__bf16)(oo * 0.70710678118f);
        }
      } else {
        bf16x4 v;
#pragma unroll
        for (int ri = 0; ri < 4; ++ri) v[ri] = (__bf16)o[ri];
        int b = growb >> 11, tok = growb & 2047;
        *(bf16x4*)&PTE[((size_t)(b * 272 + gcol)) * 2048 + tok] = v;
      }
    }
  }
}

// ---------------- MFMA flash attention (R10/R12 config — validated) --------
__global__ __launch_bounds__(256, 2) void attn_kernel(
    const __bf16* __restrict__ Grow, const __bf16* __restrict__ Gcol,
    const __bf16* __restrict__ PTE, const unsigned char* __restrict__ mask8,
    __bf16* __restrict__ msgn0, __bf16* __restrict__ msgn1,
    float* __restrict__ statP) {
  __shared__ __align__(16) unsigned char GcLo[16384];   // [32 kv][512B] swz
  __shared__ __align__(16) unsigned char GcHi[16384];   // [32 kv][512B] swz
  __shared__ __align__(16) unsigned char PtS[2][17408]; // [272 d][64B] swz

  int tid = threadIdx.x;
  int w = tid >> 6, lane = tid & 63, ln15 = lane & 15, lq = lane >> 4;
  int id = blockIdx.x;
  int b = id & 7;
  int half = (id >> 3) & 1;
  int r0 = (id >> 4) * 64;
  size_t base = (size_t)b * NN;
  __bf16* msgn = half ? msgn1 : msgn0;
  float* statB = statP + (size_t)half * MTOK * 6;

  const unsigned char* gbaseK =
      (const unsigned char*)Gcol + (base + half * 1024) * 1024;
  const unsigned char* gbaseF =
      (const unsigned char*)Grow + (base + half * 1024) * 1024;
  const unsigned char* pbase =
      (const unsigned char*)PTE + (size_t)b * 272 * 4096 + half * 2048;

  bf16x8 Af[16];
  {
    const __bf16* gr = Grow + (base + r0 + w * 16 + ln15) * 512 + lq * 8;
#pragma unroll
    for (int kk = 0; kk < 16; ++kk) Af[kk] = *(const bf16x8*)(gr + kk * 32);
  }

  float m = -1e30f, T = 0.f;
  f32x4 macc[17];
#pragma unroll
  for (int nt = 0; nt < 17; ++nt) macc[nt] = (f32x4){0.f, 0.f, 0.f, 0.f};

  int pswz = (lq ^ ((ln15 >> 1) & 3)) << 4;
  int n0 = ((ln15 >> 2) * 8) + (ln15 & 3);
  int n1 = n0 + 4;
  int s0 = (((n0 & 3) | (((n0 >> 3) & 1) << 2))) << 4;
  int s1 = (((n1 & 3) | (((n1 >> 3) & 1) << 2))) << 4;
  int srcsw = ((lane & 3) ^ ((lane >> 3) & 3)) << 4;
  int glrow = lane >> 5;
  int glb = (lane & 31) * 16;

  auto STG = [&](const unsigned char* gb, int ch, unsigned char* dst, int koff) {
#pragma unroll
    for (int i = 0; i < 4; ++i) {
      int rp = w * 8 + 2 * i;
      int r = rp + glrow;
      int sbr = glb ^ ((((r & 3) | (((r >> 3) & 1) << 2))) << 4);
      gl_lds16(gb + (size_t)(ch * 32 + r) * 1024 + koff + sbr, dst + rp * 512);
    }
  };
  auto STPT = [&](int ch, int buf) {
#pragma unroll
    for (int i = 0; i < 4; ++i) {
      int idx = w * 4 + i;
      int drow = idx * 16 + (lane >> 2);
      gl_lds16(pbase + (size_t)drow * 4096 + ch * 64 + srcsw,
               &PtS[buf][idx * 1024]);
    }
    {
      int drow = 256 + (lane >> 2);
      gl_lds16(pbase + (size_t)drow * 4096 + ch * 64 + srcsw,
               &PtS[buf][16 * 1024]);
    }
  };

  STPT(0, 0);
  STG(gbaseK, 0, GcLo, 0);
  STG(gbaseF, 0, GcHi, 512);

  for (int ch = 0; ch < 32; ++ch) {
    int cur = ch & 1;
    WAITVM(4);
    BARX();
    STPT(ch + 1, cur ^ 1);

    f32x4 sa0 = (f32x4){0.f, 0.f, 0.f, 0.f};
    f32x4 sa1 = (f32x4){0.f, 0.f, 0.f, 0.f};
    __builtin_amdgcn_s_setprio(1);
#pragma unroll
    for (int kk = 0; kk < 8; ++kk) {
      bf16x8 bv0 = *(const bf16x8*)&GcLo[n0 * 512 + ((lq * 16 + kk * 64) ^ s0)];
      sa0 = MFMA16(bv0, Af[kk], sa0);
      bf16x8 bv1 = *(const bf16x8*)&GcLo[n1 * 512 + ((lq * 16 + kk * 64) ^ s1)];
      sa1 = MFMA16(bv1, Af[kk], sa1);
    }
    __builtin_amdgcn_s_setprio(0);

    WAITVM(5);
    BARX();
    STG(gbaseK, ch + 1, GcLo, 0);

    __builtin_amdgcn_s_setprio(1);
#pragma unroll
    for (int kk = 8; kk < 16; ++kk) {
      bf16x8 bv0 = *(const bf16x8*)&GcHi[n0 * 512 + ((lq * 16 + (kk - 8) * 64) ^ s0)];
      sa0 = MFMA16(bv0, Af[kk], sa0);
      bf16x8 bv1 = *(const bf16x8*)&GcHi[n1 * 512 + ((lq * 16 + (kk - 8) * 64) ^ s1)];
      sa1 = MFMA16(bv1, Af[kk], sa1);
    }
    __builtin_amdgcn_s_setprio(0);

    float sv[8] = {sa0[0], sa0[1], sa0[2], sa0[3], sa1[0], sa1[1], sa1[2], sa1[3]};
    unsigned long long mk = *(const unsigned long long*)(
        mask8 + base + half * 1024 + (size_t)ch * 32 + lq * 8);

    float mt = -1e30f;
#pragma unroll
    for (int i = 0; i < 8; ++i) {
      float li = ((mk >> (8 * i)) & 0xffull) ? sv[i] : -1e30f;
      mt = fmaxf(mt, li);
    }
    mt = fmaxf(mt, __shfl_xor(mt, 16));
    mt = fmaxf(mt, __shfl_xor(mt, 32));
    float mnew = fmaxf(m, mt);
    if (__any(mnew > m + 8.0f)) {      // defer-max threshold (T13)
      float ci = __expf(m - mnew);
      float cir[4];
#pragma unroll
      for (int r = 0; r < 4; ++r)
        cir[r] = __shfl(ci, (lane & 48) + ((lane >> 2) & 12) + r);
#pragma unroll
      for (int nt = 0; nt < 17; ++nt) {
        macc[nt][0] *= cir[0]; macc[nt][1] *= cir[1];
        macc[nt][2] *= cir[2]; macc[nt][3] *= cir[3];
      }
      T *= ci;
      m = mnew;
    }
    float e[8], tl = 0.f;
#pragma unroll
    for (int i = 0; i < 8; ++i) {
      float ei = ((mk >> (8 * i)) & 0xffull) ? __expf(sv[i] - m) : 0.f;
      e[i] = ei;
      tl += ei * sv[i];
    }
    tl += __shfl_xor(tl, 16);
    tl += __shfl_xor(tl, 32);
    T += tl;
    bf16x8 ef;
#pragma unroll
    for (int i = 0; i < 8; ++i) ef[i] = (__bf16)e[i];

    __builtin_amdgcn_s_setprio(1);
#pragma unroll
    for (int nt = 0; nt < 17; ++nt) {
      int drow = nt * 16 + ln15;
      bf16x8 pv = *(const bf16x8*)&PtS[cur][drow * 64 + pswz];
      macc[nt] = MFMA16(ef, pv, macc[nt]);
    }
    __builtin_amdgcn_s_setprio(0);

    BARX();
    STG(gbaseF, ch + 1, GcHi, 512);
  }
  WAITVM(0);

#pragma unroll
  for (int r = 0; r < 4; ++r) {
    int grow = r0 + w * 16 + lq * 4 + r;
    size_t row = base + grow;
    float Z = __shfl(macc[16][r], (lane & 48) + 2);
    float invZ = (Z > 0.f) ? (1.0f / Z) : 0.f;
#pragma unroll
    for (int nt = 0; nt < 16; ++nt)
      msgn[row * 256 + nt * 16 + ln15] = (__bf16)(macc[nt][r] * invZ);
    float Tm = __shfl(macc[16][r], (lane & 48) + 0);
    float Th = __shfl(macc[16][r], (lane & 48) + 1);
    float Tr = __shfl(T, (lane & 48) + ((lane >> 2) & 12) + r);
    float mr = __shfl(m, (lane & 48) + ((lane >> 2) & 12) + r);
    if (ln15 == 0) {
      float* stt = statB + row * 6;
      stt[0] = mr; stt[1] = Tr; stt[2] = Z; stt[3] = Tm; stt[4] = Th;
    }
  }
}

// ---------------- merge halves (weighted bf16 partials) ----------------
__global__ __launch_bounds__(256) void merge_kernel(
    const __bf16* __restrict__ msgn0, const __bf16* __restrict__ msgn1,
    const float* __restrict__ statP, const unsigned char* __restrict__ mask8,
    __bf16* __restrict__ MSG16, float* __restrict__ entr,
    float* __restrict__ monr, float* __restrict__ hubr) {
  int row = blockIdx.x * 4 + (threadIdx.x >> 6);
  int lane = threadIdx.x & 63;
  const float* s0 = statP + (size_t)row * 6;
  const float* s1 = statP + (size_t)(MTOK + row) * 6;
  float m0 = s0[0], T0 = s0[1], Z0 = s0[2], Tm0 = s0[3], Th0 = s0[4];
  float m1 = s1[0], T1 = s1[1], Z1 = s1[2], Tm1 = s1[3], Th1 = s1[4];
  int valid = mask8[row] != 0;
  float mm = fmaxf(m0, m1);
  float c0 = __expf(m0 - mm), c1 = __expf(m1 - mm);
  float w0 = c0 * Z0, w1 = c1 * Z1;
  float Z = w0 + w1;
  int ok = valid && (Z > 0.f);
  float invZ = ok ? (1.0f / Z) : 0.0f;
  float rw0 = w0 * invZ, rw1 = w1 * invZ;
  bf16x4 p0 = *(const bf16x4*)(msgn0 + (size_t)row * 256 + lane * 4);
  bf16x4 p1 = *(const bf16x4*)(msgn1 + (size_t)row * 256 + lane * 4);
  bf16x4 o;
#pragma unroll
  for (int q = 0; q < 4; ++q)
    o[q] = (__bf16)(rw0 * (float)p0[q] + rw1 * (float)p1[q]);
  *(bf16x4*)&MSG16[(size_t)row * 256 + lane * 4] = o;
  if (lane == 0) {
    float T = c0 * T0 + c1 * T1;
    float Tm = c0 * Tm0 + c1 * Tm1;
    float Th = c0 * Th0 + c1 * Th1;
    entr[row] = ok ? (__logf(Z) + mm - T * invZ) : 0.0f;
    monr[row] = ok ? (Tm * invZ) : 0.0f;
    hubr[row] = ok ? (Th * invZ) : 0.0f;
  }
}

// -------- MFMA GEMM (gate / out), tile 128x128, pipelined dbuf staging -----
// Per kt: WAITVM(0) (loads issued a full iteration earlier -> cheap), one
// barrier (predates overwrite of buffer last read 2 iters ago), STAGE(kt+1),
// 32 MFMA. MODE 4: gm = bf16(sigmoid([x|msg]@Wg+bg)*msg); 5: out = x+gm@Wo+bo.
template <int K, int MODE>
__global__ __launch_bounds__(256, 2) void gemmb_kernel(
    const __bf16* __restrict__ A0, const __bf16* __restrict__ A1,
    const __bf16* __restrict__ WT, const float* __restrict__ bias,
    const float* __restrict__ xf, const __bf16* __restrict__ msg16,
    void* __restrict__ dst0) {
  __shared__ __align__(16) unsigned char As[2][128 * 128];
  __shared__ __align__(16) unsigned char Bs[2][128 * 128];
  int tid = threadIdx.x;
  int w = tid >> 6, lane = tid & 63, ln15 = lane & 15, lq = lane >> 4;
  int wr = w >> 1, wc = w & 1;
  int row0 = blockIdx.y * 128, col0 = blockIdx.x * 128;
  f32x4 acc[4][4];
#pragma unroll
  for (int i = 0; i < 4; ++i)
#pragma unroll
    for (int j = 0; j < 4; ++j) acc[i][j] = (f32x4){0.f, 0.f, 0.f, 0.f};

  int lr = lane >> 3;
  int sb = ((lane & 7) * 16) ^ ((lr & 7) << 4);

  auto STAGE = [&](int kt, int bufi) {
    const __bf16* Ab = A0;
    int ktl = kt;
    if (K == 512 && kt >= 4) { Ab = A1; ktl = kt - 4; }
#pragma unroll
    for (int i2 = 0; i2 < 4; ++i2) {
      int idx = w * 4 + i2;
      int grow = row0 + idx * 8 + lr;
      gl_lds16((const unsigned char*)Ab + (size_t)grow * 512 + ktl * 128 + sb,
               &As[bufi][idx * 1024]);
    }
#pragma unroll
    for (int i2 = 0; i2 < 4; ++i2) {
      int idx = w * 4 + i2;
      int gcol = col0 + idx * 8 + lr;
      gl_lds16((const unsigned char*)WT + (size_t)gcol * (K * 2) + kt * 128 + sb,
               &Bs[bufi][idx * 1024]);
    }
  };

  STAGE(0, 0);
  for (int kt = 0; kt < K / 64; ++kt) {
    int buf = kt & 1;
    WAITVM(0);              // kt's 8 loads landed (issued last iteration)
    BARX();                 // all waves past iter kt-1 compute; stage visible
    if (kt + 1 < K / 64) STAGE(kt + 1, buf ^ 1);
#pragma unroll
    for (int ks = 0; ks < 2; ++ks) {
      bf16x8 af[4], bfr[4];
#pragma unroll
      for (int i = 0; i < 4; ++i) {
        int rl = wr * 64 + i * 16 + ln15;
        int byteoff = (lq * 16 + ks * 64) ^ ((rl & 7) << 4);
        af[i] = *(const bf16x8*)&As[buf][rl * 128 + byteoff];
      }
#pragma unroll
      for (int j = 0; j < 4; ++j) {
        int cl = wc * 64 + j * 16 + ln15;
        int byteoff = (lq * 16 + ks * 64) ^ ((cl & 7) << 4);
        bfr[j] = *(const bf16x8*)&Bs[buf][cl * 128 + byteoff];
      }
      __builtin_amdgcn_s_setprio(1);
#pragma unroll
      for (int i = 0; i < 4; ++i)
#pragma unroll
        for (int j = 0; j < 4; ++j) acc[i][j] = MFMA16(af[i], bfr[j], acc[i][j]);
      __builtin_amdgcn_s_setprio(0);
    }
  }
  float bj[4];
#pragma unroll
  for (int j = 0; j < 4; ++j) bj[j] = bias[col0 + wc * 64 + j * 16 + ln15];
#pragma unroll
  for (int i = 0; i < 4; ++i) {
#pragma unroll
    for (int ri = 0; ri < 4; ++ri) {
      int grow = row0 + wr * 64 + i * 16 + lq * 4 + ri;
#pragma unroll
      for (int j = 0; j < 4; ++j) {
        int gcol = col0 + wc * 64 + j * 16 + ln15;
        float o = acc[i][j][ri] + bj[j];
        if (MODE == 4) {
          float sg = 1.0f / (1.0f + __expf(-o));
          float mv = (float)msg16[(size_t)grow * 256 + gcol];
          ((__bf16*)dst0)[(size_t)grow * 256 + gcol] = (__bf16)(sg * mv);
        } else {
          ((float*)dst0)[(size_t)grow * 256 + gcol] =
              o + xf[(size_t)grow * 256 + gcol];
        }
      }
    }
  }
}

// ---------------- two-stage scalar reduction ----------------
__device__ __forceinline__ float block_sum(float v, float* sh) {
  __syncthreads();
  sh[threadIdx.x] = v;
  __syncthreads();
  for (int s = 128; s > 0; s >>= 1) {
    if ((int)threadIdx.x < s) sh[threadIdx.x] += sh[threadIdx.x + s];
    __syncthreads();
  }
  return sh[0];
}

__global__ __launch_bounds__(256) void reduce1_kernel(
    const float* __restrict__ entr, const float* __restrict__ monr,
    const float* __restrict__ hubr, float* __restrict__ partial) {
  __shared__ float sh[256];
  int t = blockIdx.x * 256 + threadIdx.x;
  float es = entr[t], ms = monr[t], hs = hubr[t];
  float e = block_sum(es, sh);
  float mo = block_sum(ms, sh);
  float hu = block_sum(hs, sh);
  if (threadIdx.x == 0) {
    partial[blockIdx.x * 4 + 0] = e;
    partial[blockIdx.x * 4 + 1] = mo;
    partial[blockIdx.x * 4 + 2] = hu;
  }
}

__global__ __launch_bounds__(256) void reduce2_kernel(
    const float* __restrict__ partial, const float* __restrict__ monf,
    const float* __restrict__ hubf, float* __restrict__ out3) {
  __shared__ float sh[256];
  float es = 0.f, ms = 0.f, hs = 0.f, cmf = 0.f, chf = 0.f;
  if (threadIdx.x < 64) {
    es = partial[threadIdx.x * 4 + 0];
    ms = partial[threadIdx.x * 4 + 1];
    hs = partial[threadIdx.x * 4 + 2];
  }
  for (int j = threadIdx.x; j < NN; j += 256) { cmf += monf[j]; chf += hubf[j]; }
  float esum = block_sum(es, sh);
  float msum = block_sum(ms, sh);
  float hsum = block_sum(hs, sh);
  float cmsum = block_sum(cmf, sh);
  float chsum = block_sum(chf, sh);
  if (threadIdx.x == 0) {
    out3[0] = esum / 16384.0f;
    out3[1] = (cmsum > 0.f) ? (msum / (cmsum * 16384.0f)) : 0.0f;
    out3[2] = (chsum > 0.f) ? (hsum / (chsum * 16384.0f)) : 0.0f;
  }
}

extern "C" void kernel_launch(void* const* d_in, const int* in_sizes, int n_in,
                              void* d_out, int out_size, void* d_ws, size_t ws_size,
                              hipStream_t stream) {
  const float* x = (const float*)d_in[0];
  const int* roles = (const int*)d_in[1];
  const void* mraw = d_in[2];
  const float* gamma = (const float*)d_in[3];
  const float* beta = (const float*)d_in[4];
  const float* remb = (const float*)d_in[5];
  const float* Wq = (const float*)d_in[6];
  const float* bq = (const float*)d_in[7];
  const float* Wk = (const float*)d_in[8];
  const float* bk = (const float*)d_in[9];
  const float* Ws = (const float*)d_in[10];
  const float* bs = (const float*)d_in[11];
  const float* Wp = (const float*)d_in[12];
  const float* bp = (const float*)d_in[13];
  const float* Wo = (const float*)d_in[14];
  const float* bo = (const float*)d_in[15];
  const float* Wg = (const float*)d_in[16];
  const float* bg = (const float*)d_in[17];

  float* ws = (float*)d_ws;
  __bf16* X16 = (__bf16*)(ws + OFF_X16);
  __bf16* N16 = (__bf16*)(ws + OFF_N16);
  __bf16* H16 = (__bf16*)(ws + OFF_H16);
  __bf16* Grow = (__bf16*)(ws + OFF_GROW);
  __bf16* Gcol = (__bf16*)(ws + OFF_GCOL);
  __bf16* PTE = (__bf16*)(ws + OFF_PTE);
  __bf16* WT = (__bf16*)(ws + OFF_WT);
  float* statP = ws + OFF_STAT;
  __bf16* msgn0 = (__bf16*)(ws + OFF_MSGN0);
  __bf16* msgn1 = (__bf16*)(ws + OFF_MSGN1);
  float* partial = ws + OFF_PART;
  __bf16* MSG16 = (__bf16*)(ws + OFF_MSG16);
  __bf16* GM16 = (__bf16*)(ws + OFF_GM16);
  float* entr = ws + OFF_ENT;
  float* monr = ws + OFF_MONR;
  float* hubr = ws + OFF_HUBR;
  float* monfp = ws + OFF_MONF;
  float* hubfp = ws + OFF_HUBF;
  unsigned char* mask8 = (unsigned char*)(ws + OFF_MASK);
  float* out = (float*)d_out;

  __bf16* WTg = WT + 262144;
  __bf16* WTo = WT + 393216;

  setup_kernel<<<4416, 256, 0, stream>>>(x, roles, mraw, gamma, beta, remb,
                                         Wq, Wk, Ws, Wp, Wg, Wo,
                                         X16, N16, H16, WT, mask8, monfp,
                                         hubfp, PTE);
  proj4_kernel<<<dim3(2, 128, 4), 256, 0, stream>>>(
      H16, N16, WT, bq, bk, bs, bp, roles, remb, Grow, Gcol, PTE);
  attn_kernel<<<512, 256, 0, stream>>>(Grow, Gcol, PTE, mask8, msgn0, msgn1,
                                       statP);
  merge_kernel<<<4096, 256, 0, stream>>>(msgn0, msgn1, statP, mask8, MSG16,
                                         entr, monr, hubr);
  gemmb_kernel<512, 4><<<dim3(2, 128), 256, 0, stream>>>(
      X16, MSG16, WTg, bg, nullptr, MSG16, GM16);
  gemmb_kernel<256, 5><<<dim3(2, 128), 256, 0, stream>>>(
      GM16, nullptr, WTo, bo, x, nullptr, out);
  reduce1_kernel<<<64, 256, 0, stream>>>(entr, monr, hubr, partial);
  reduce2_kernel<<<1, 256, 0, stream>>>(partial, monfp, hubfp, out + 4194304);
}

// Round 15
// 162.792 us; speedup vs baseline: 1.4664x; 1.0088x over previous
//
#include <hip/hip_runtime.h>
#include <math.h>

#define BB 8
#define NN 2048
#define DD 256
#define MTOK 16384

typedef __bf16 bf16x8 __attribute__((ext_vector_type(8)));
typedef __bf16 bf16x4 __attribute__((ext_vector_type(4)));
typedef float f32x4 __attribute__((ext_vector_type(4)));

#define MFMA16(a, b, c) __builtin_amdgcn_mfma_f32_16x16x32_bf16(a, b, c, 0, 0, 0)

// raw barrier + compiler memory fence (no implicit vmcnt(0) drain)
#define BARX()                              \
  do {                                      \
    asm volatile("" ::: "memory");          \
    __builtin_amdgcn_s_barrier();           \
    asm volatile("" ::: "memory");          \
  } while (0)
// counted vmem wait (literal N) + scheduling fence
#define WAITVM(N)                                              \
  do {                                                         \
    asm volatile("s_waitcnt vmcnt(" #N ")" ::: "memory");      \
    __builtin_amdgcn_sched_barrier(0);                         \
  } while (0)

// ---- workspace layout (float offsets) ----
#define OFF_X16    0ull          // bf16 [16384][256]
#define OFF_N16    2097152ull    // bf16 [16384][256]
#define OFF_H16    4194304ull    // bf16 [16384][256]
#define OFF_GROW   8388608ull    // bf16 [16384][512]  ([q/16 | fs*sqrt(.5)])
#define OFF_GCOL   12582912ull   // bf16 [16384][512]  ([k    | unused hi])
#define OFF_PTE    16777216ull   // bf16 [8][272][2048]
#define OFF_WT     19005440ull   // bf16 weights transposed
#define OFF_STAT   19234816ull   // f32 [2][16384][6] attn half-stats
#define OFF_PARTM  23625728ull   // f32 [4096][4] merge partial sums
#define OFF_MONF   23674880ull
#define OFF_HUBF   23676928ull
#define OFF_MASK   23678976ull   // 16384 bytes
// aliases (dead-region reuse):
#define OFF_MSGN0  OFF_N16       // bf16 [16384][256]; N16 dead after proj
#define OFF_MSGN1  OFF_H16       // bf16 [16384][256]; H16 dead after proj
#define OFF_MSG16  OFF_PTE       // bf16 [16384][256]; PTE dead after attn
#define OFF_GM16   OFF_GROW      // bf16 [16384][256]; GROW dead after attn

__device__ __forceinline__ void gl_lds16(const void* g, void* l) {
  __builtin_amdgcn_global_load_lds(
      (const __attribute__((address_space(1))) unsigned int*)g,
      (__attribute__((address_space(3))) unsigned int*)l, 16, 0, 0);
}

// --- merged setup: prep(0..4095) | wt(4096..4287) | mask(4288..4351) |
//     fill_pte(4352..4415) — all uniform-duration block ranges, no tails ---
__global__ __launch_bounds__(256) void setup_kernel(
    const float* __restrict__ x, const int* __restrict__ roles,
    const void* __restrict__ mraw,
    const float* __restrict__ gamma, const float* __restrict__ beta,
    const float* __restrict__ role_emb,
    const float* __restrict__ Wq, const float* __restrict__ Wk,
    const float* __restrict__ Ws, const float* __restrict__ Wp,
    const float* __restrict__ Wg, const float* __restrict__ Wo,
    __bf16* __restrict__ X16, __bf16* __restrict__ N16,
    __bf16* __restrict__ H16, __bf16* __restrict__ WT,
    unsigned char* __restrict__ mask8,
    float* __restrict__ monf, float* __restrict__ hubf,
    __bf16* __restrict__ PTE) {
  __shared__ float T[64][65];
  int bid = blockIdx.x;
  int tid = threadIdx.x;
  if (bid < 4096) {
    int t = bid * 4 + (tid >> 6);
    int lane = tid & 63;
    size_t off = (size_t)t * DD + lane * 4;
    float4 xv = *(const float4*)(x + off);
    float s = xv.x + xv.y + xv.z + xv.w;
    float ss = xv.x * xv.x + xv.y * xv.y + xv.z * xv.z + xv.w * xv.w;
#pragma unroll
    for (int m = 1; m < 64; m <<= 1) {
      s += __shfl_xor(s, m, 64);
      ss += __shfl_xor(ss, m, 64);
    }
    float mu = s * (1.0f / 256.0f);
    float var = ss * (1.0f / 256.0f) - mu * mu;
    float inv = rsqrtf(var + 1e-5f);
    float4 g = *(const float4*)(gamma + lane * 4);
    float4 be = *(const float4*)(beta + lane * 4);
    float nv[4];
    nv[0] = (xv.x - mu) * inv * g.x + be.x;
    nv[1] = (xv.y - mu) * inv * g.y + be.y;
    nv[2] = (xv.z - mu) * inv * g.z + be.z;
    nv[3] = (xv.w - mu) * inv * g.w + be.w;
    int role = roles[t];
    float4 rb = *(const float4*)(role_emb + (size_t)role * DD + lane * 4);
    float rbv[4] = {rb.x, rb.y, rb.z, rb.w};
    bf16x4 xo, no, ho;
    float xf[4] = {xv.x, xv.y, xv.z, xv.w};
#pragma unroll
    for (int q = 0; q < 4; ++q) {
      xo[q] = (__bf16)xf[q];
      no[q] = (__bf16)nv[q];
      ho[q] = (__bf16)(nv[q] + rbv[q]);
    }
    *(bf16x4*)&X16[off] = xo;
    *(bf16x4*)&N16[off] = no;
    *(bf16x4*)&H16[off] = ho;
  } else if (bid < 4288) {
    int wblk = bid - 4096;
    int z = wblk >> 5, rem = wblk & 31;
    int bx = rem & 3, by = rem >> 2;
    const float* src;
    int K;
    size_t doff;
    switch (z) {
      case 0: src = Wq; K = 256; doff = 0; break;
      case 1: src = Wk; K = 256; doff = 65536; break;
      case 2: src = Ws; K = 256; doff = 131072; break;
      case 3: src = Wp; K = 256; doff = 196608; break;
      case 4: src = Wg; K = 512; doff = 262144; break;
      default: src = Wo; K = 256; doff = 393216; break;
    }
    int k0 = by * 64;
    if (k0 >= K) return;
    int n0 = bx * 64;
#pragma unroll
    for (int p = 0; p < 16; ++p) {
      int idx = p * 256 + tid;
      int r = idx >> 6, c = idx & 63;
      T[r][c] = src[(size_t)(k0 + r) * 256 + n0 + c];
    }
    __syncthreads();
#pragma unroll
    for (int p = 0; p < 16; ++p) {
      int idx = p * 256 + tid;
      int n = idx >> 6, k = idx & 63;
      WT[doff + (size_t)(n0 + n) * K + k0 + k] = (__bf16)T[k][n];
    }
  } else if (bid < 4352) {
    int* csh = (int*)&T[0][0];
    if (tid == 0) { csh[0] = 0; csh[1] = 0; }
    __syncthreads();
    const unsigned char* raw = (const unsigned char*)mraw;
    int c0 = 0, c1 = 0;
    for (int i = tid; i < 4096; i += 256) {
      int nz = (raw[i] != 0) ? 1 : 0;
      if ((i & 3) == 0) c0 += nz; else c1 += nz;
    }
    atomicAdd(&csh[0], c0);
    atomicAdd(&csh[1], c1);
    __syncthreads();
    int k = (csh[0] == 0) ? 2 : ((csh[1] == 0) ? 0 : 1);
    int t = (bid - 4288) * 256 + tid;
    if (t < MTOK) {
      int v;
      if (k == 1)      v = (raw[t] != 0);
      else if (k == 0) v = (((const int*)mraw)[t] != 0);
      else             v = (((const float*)mraw)[t] != 0.0f);
      mask8[t] = (unsigned char)v;
    }
    if (t < NN) {
      int mon = 0, hub = 0;
#pragma unroll
      for (int b = 0; b < BB; ++b) {
        int r = roles[b * NN + t];
        mon |= (r == 2) ? 1 : 0;
        hub |= (r == 1) ? 1 : 0;
      }
      monf[t] = (float)mon;
      hubf[t] = (float)hub;
    }
  } else {
    // fill_pte: PTE stat rows 256..271 (mon/hub from roles, uniform blocks)
    int idx = (bid - 4352) * 256 + tid;   // 16384 = b(8) x col(2048)
    int b = idx >> 11, col = idx & 2047;
    int mon = 0, hub = 0;
#pragma unroll
    for (int bb = 0; bb < BB; ++bb) {
      int r = roles[bb * NN + col];
      mon |= (r == 2) ? 1 : 0;
      hub |= (r == 1) ? 1 : 0;
    }
    size_t rbase = ((size_t)(b * 272 + 256)) * 2048 + col;
    PTE[rbase] = (__bf16)(float)mon;
    PTE[rbase + 2048] = (__bf16)(float)hub;
    PTE[rbase + 2 * 2048] = (__bf16)1.0f;
#pragma unroll
    for (int r = 3; r < 16; ++r) PTE[rbase + (size_t)r * 2048] = (__bf16)0.0f;
  }
}

// -------- fused q/k/fs/p projections (z = 0..3), K=256, tile 128x128 --------
// fs (z==2) stored ONCE in Grow+256 (Gcol hi-half unused).
__global__ __launch_bounds__(256, 4) void proj4_kernel(
    const __bf16* __restrict__ H16, const __bf16* __restrict__ N16,
    const __bf16* __restrict__ WT,
    const float* __restrict__ bq, const float* __restrict__ bk,
    const float* __restrict__ bs, const float* __restrict__ bp,
    const int* __restrict__ roles, const float* __restrict__ remb,
    __bf16* __restrict__ Grow, __bf16* __restrict__ Gcol,
    __bf16* __restrict__ PTE) {
  __shared__ __align__(16) unsigned char As[128 * 128];
  __shared__ __align__(16) unsigned char Bs[128 * 128];
  int z = blockIdx.z;
  const __bf16* A = (z == 3) ? N16 : H16;
  const __bf16* W = WT + (size_t)z * 65536;
  const float* bias = (z == 0) ? bq : (z == 1) ? bk : (z == 2) ? bs : bp;

  int tid = threadIdx.x;
  int w = tid >> 6, lane = tid & 63, ln15 = lane & 15, lq = lane >> 4;
  int wr = w >> 1, wc = w & 1;
  int row0 = blockIdx.y * 128, col0 = blockIdx.x * 128;
  f32x4 acc[4][4];
#pragma unroll
  for (int i = 0; i < 4; ++i)
#pragma unroll
    for (int j = 0; j < 4; ++j) acc[i][j] = (f32x4){0.f, 0.f, 0.f, 0.f};

  int lr = lane >> 3;
  int sb = ((lane & 7) * 16) ^ ((lr & 7) << 4);

  for (int kt = 0; kt < 4; ++kt) {
    __syncthreads();
#pragma unroll
    for (int i2 = 0; i2 < 4; ++i2) {
      int idx = w * 4 + i2;
      int grow = row0 + idx * 8 + lr;
      gl_lds16((const unsigned char*)A + (size_t)grow * 512 + kt * 128 + sb,
               As + idx * 1024);
    }
#pragma unroll
    for (int i2 = 0; i2 < 4; ++i2) {
      int idx = w * 4 + i2;
      int gcol = col0 + idx * 8 + lr;
      gl_lds16((const unsigned char*)W + (size_t)gcol * 512 + kt * 128 + sb,
               Bs + idx * 1024);
    }
    __syncthreads();
#pragma unroll
    for (int ks = 0; ks < 2; ++ks) {
      bf16x8 af[4], bfr[4];
#pragma unroll
      for (int i = 0; i < 4; ++i) {
        int rl = wr * 64 + i * 16 + ln15;
        int byteoff = (lq * 16 + ks * 64) ^ ((rl & 7) << 4);
        af[i] = *(const bf16x8*)(As + rl * 128 + byteoff);
      }
#pragma unroll
      for (int j = 0; j < 4; ++j) {
        int cl = wc * 64 + j * 16 + ln15;
        int byteoff = (lq * 16 + ks * 64) ^ ((cl & 7) << 4);
        bfr[j] = *(const bf16x8*)(Bs + cl * 128 + byteoff);
      }
#pragma unroll
      for (int i = 0; i < 4; ++i)
#pragma unroll
        for (int j = 0; j < 4; ++j) acc[i][j] = MFMA16(af[i], bfr[j], acc[i][j]);
    }
  }
  float bj[4];
#pragma unroll
  for (int j = 0; j < 4; ++j) bj[j] = bias[col0 + wc * 64 + j * 16 + ln15];
#pragma unroll
  for (int i = 0; i < 4; ++i) {
#pragma unroll
    for (int j = 0; j < 4; ++j) {
      int gcol = col0 + wc * 64 + j * 16 + ln15;
      int growb = row0 + wr * 64 + i * 16 + lq * 4;
      float o[4];
#pragma unroll
      for (int ri = 0; ri < 4; ++ri) o[ri] = acc[i][j][ri] + bj[j];
      if (z == 0) {
#pragma unroll
        for (int ri = 0; ri < 4; ++ri)
          Grow[(size_t)(growb + ri) * 512 + gcol] = (__bf16)(o[ri] * 0.0625f);
      } else if (z == 1) {
#pragma unroll
        for (int ri = 0; ri < 4; ++ri)
          Gcol[(size_t)(growb + ri) * 512 + gcol] = (__bf16)o[ri];
      } else if (z == 2) {
#pragma unroll
        for (int ri = 0; ri < 4; ++ri) {
          float oo = o[ri] + remb[(size_t)roles[growb + ri] * 256 + gcol];
          Grow[(size_t)(growb + ri) * 512 + 256 + gcol] =
              (__bf16)(oo * 0.70710678118f);
        }
      } else {
        bf16x4 v;
#pragma unroll
        for (int ri = 0; ri < 4; ++ri) v[ri] = (__bf16)o[ri];
        int b = growb >> 11, tok = growb & 2047;
        *(bf16x4*)&PTE[((size_t)(b * 272 + gcol)) * 2048 + tok] = v;
      }
    }
  }
}

// ---------------- MFMA flash attention (R10/R12 config — validated) --------
__global__ __launch_bounds__(256, 2) void attn_kernel(
    const __bf16* __restrict__ Grow, const __bf16* __restrict__ Gcol,
    const __bf16* __restrict__ PTE, const unsigned char* __restrict__ mask8,
    __bf16* __restrict__ msgn0, __bf16* __restrict__ msgn1,
    float* __restrict__ statP) {
  __shared__ __align__(16) unsigned char GcLo[16384];   // [32 kv][512B] swz
  __shared__ __align__(16) unsigned char GcHi[16384];   // [32 kv][512B] swz
  __shared__ __align__(16) unsigned char PtS[2][17408]; // [272 d][64B] swz

  int tid = threadIdx.x;
  int w = tid >> 6, lane = tid & 63, ln15 = lane & 15, lq = lane >> 4;
  int id = blockIdx.x;
  int b = id & 7;
  int half = (id >> 3) & 1;
  int r0 = (id >> 4) * 64;
  size_t base = (size_t)b * NN;
  __bf16* msgn = half ? msgn1 : msgn0;
  float* statB = statP + (size_t)half * MTOK * 6;

  const unsigned char* gbaseK =
      (const unsigned char*)Gcol + (base + half * 1024) * 1024;
  const unsigned char* gbaseF =
      (const unsigned char*)Grow + (base + half * 1024) * 1024;
  const unsigned char* pbase =
      (const unsigned char*)PTE + (size_t)b * 272 * 4096 + half * 2048;

  bf16x8 Af[16];
  {
    const __bf16* gr = Grow + (base + r0 + w * 16 + ln15) * 512 + lq * 8;
#pragma unroll
    for (int kk = 0; kk < 16; ++kk) Af[kk] = *(const bf16x8*)(gr + kk * 32);
  }

  float m = -1e30f, T = 0.f;
  f32x4 macc[17];
#pragma unroll
  for (int nt = 0; nt < 17; ++nt) macc[nt] = (f32x4){0.f, 0.f, 0.f, 0.f};

  int pswz = (lq ^ ((ln15 >> 1) & 3)) << 4;
  int n0 = ((ln15 >> 2) * 8) + (ln15 & 3);
  int n1 = n0 + 4;
  int s0 = (((n0 & 3) | (((n0 >> 3) & 1) << 2))) << 4;
  int s1 = (((n1 & 3) | (((n1 >> 3) & 1) << 2))) << 4;
  int srcsw = ((lane & 3) ^ ((lane >> 3) & 3)) << 4;
  int glrow = lane >> 5;
  int glb = (lane & 31) * 16;

  auto STG = [&](const unsigned char* gb, int ch, unsigned char* dst, int koff) {
#pragma unroll
    for (int i = 0; i < 4; ++i) {
      int rp = w * 8 + 2 * i;
      int r = rp + glrow;
      int sbr = glb ^ ((((r & 3) | (((r >> 3) & 1) << 2))) << 4);
      gl_lds16(gb + (size_t)(ch * 32 + r) * 1024 + koff + sbr, dst + rp * 512);
    }
  };
  auto STPT = [&](int ch, int buf) {
#pragma unroll
    for (int i = 0; i < 4; ++i) {
      int idx = w * 4 + i;
      int drow = idx * 16 + (lane >> 2);
      gl_lds16(pbase + (size_t)drow * 4096 + ch * 64 + srcsw,
               &PtS[buf][idx * 1024]);
    }
    {
      int drow = 256 + (lane >> 2);
      gl_lds16(pbase + (size_t)drow * 4096 + ch * 64 + srcsw,
               &PtS[buf][16 * 1024]);
    }
  };

  STPT(0, 0);
  STG(gbaseK, 0, GcLo, 0);
  STG(gbaseF, 0, GcHi, 512);

  for (int ch = 0; ch < 32; ++ch) {
    int cur = ch & 1;
    WAITVM(4);
    BARX();
    STPT(ch + 1, cur ^ 1);

    f32x4 sa0 = (f32x4){0.f, 0.f, 0.f, 0.f};
    f32x4 sa1 = (f32x4){0.f, 0.f, 0.f, 0.f};
    __builtin_amdgcn_s_setprio(1);
#pragma unroll
    for (int kk = 0; kk < 8; ++kk) {
      bf16x8 bv0 = *(const bf16x8*)&GcLo[n0 * 512 + ((lq * 16 + kk * 64) ^ s0)];
      sa0 = MFMA16(bv0, Af[kk], sa0);
      bf16x8 bv1 = *(const bf16x8*)&GcLo[n1 * 512 + ((lq * 16 + kk * 64) ^ s1)];
      sa1 = MFMA16(bv1, Af[kk], sa1);
    }
    __builtin_amdgcn_s_setprio(0);

    WAITVM(5);
    BARX();
    STG(gbaseK, ch + 1, GcLo, 0);

    __builtin_amdgcn_s_setprio(1);
#pragma unroll
    for (int kk = 8; kk < 16; ++kk) {
      bf16x8 bv0 = *(const bf16x8*)&GcHi[n0 * 512 + ((lq * 16 + (kk - 8) * 64) ^ s0)];
      sa0 = MFMA16(bv0, Af[kk], sa0);
      bf16x8 bv1 = *(const bf16x8*)&GcHi[n1 * 512 + ((lq * 16 + (kk - 8) * 64) ^ s1)];
      sa1 = MFMA16(bv1, Af[kk], sa1);
    }
    __builtin_amdgcn_s_setprio(0);

    float sv[8] = {sa0[0], sa0[1], sa0[2], sa0[3], sa1[0], sa1[1], sa1[2], sa1[3]};
    unsigned long long mk = *(const unsigned long long*)(
        mask8 + base + half * 1024 + (size_t)ch * 32 + lq * 8);

    float mt = -1e30f;
#pragma unroll
    for (int i = 0; i < 8; ++i) {
      float li = ((mk >> (8 * i)) & 0xffull) ? sv[i] : -1e30f;
      mt = fmaxf(mt, li);
    }
    mt = fmaxf(mt, __shfl_xor(mt, 16));
    mt = fmaxf(mt, __shfl_xor(mt, 32));
    float mnew = fmaxf(m, mt);
    if (__any(mnew > m + 8.0f)) {      // defer-max threshold (T13)
      float ci = __expf(m - mnew);
      float cir[4];
#pragma unroll
      for (int r = 0; r < 4; ++r)
        cir[r] = __shfl(ci, (lane & 48) + ((lane >> 2) & 12) + r);
#pragma unroll
      for (int nt = 0; nt < 17; ++nt) {
        macc[nt][0] *= cir[0]; macc[nt][1] *= cir[1];
        macc[nt][2] *= cir[2]; macc[nt][3] *= cir[3];
      }
      T *= ci;
      m = mnew;
    }
    float e[8], tl = 0.f;
#pragma unroll
    for (int i = 0; i < 8; ++i) {
      float ei = ((mk >> (8 * i)) & 0xffull) ? __expf(sv[i] - m) : 0.f;
      e[i] = ei;
      tl += ei * sv[i];
    }
    tl += __shfl_xor(tl, 16);
    tl += __shfl_xor(tl, 32);
    T += tl;
    bf16x8 ef;
#pragma unroll
    for (int i = 0; i < 8; ++i) ef[i] = (__bf16)e[i];

    __builtin_amdgcn_s_setprio(1);
#pragma unroll
    for (int nt = 0; nt < 17; ++nt) {
      int drow = nt * 16 + ln15;
      bf16x8 pv = *(const bf16x8*)&PtS[cur][drow * 64 + pswz];
      macc[nt] = MFMA16(ef, pv, macc[nt]);
    }
    __builtin_amdgcn_s_setprio(0);

    BARX();
    STG(gbaseF, ch + 1, GcHi, 512);
  }
  WAITVM(0);

#pragma unroll
  for (int r = 0; r < 4; ++r) {
    int grow = r0 + w * 16 + lq * 4 + r;
    size_t row = base + grow;
    float Z = __shfl(macc[16][r], (lane & 48) + 2);
    float invZ = (Z > 0.f) ? (1.0f / Z) : 0.f;
#pragma unroll
    for (int nt = 0; nt < 16; ++nt)
      msgn[row * 256 + nt * 16 + ln15] = (__bf16)(macc[nt][r] * invZ);
    float Tm = __shfl(macc[16][r], (lane & 48) + 0);
    float Th = __shfl(macc[16][r], (lane & 48) + 1);
    float Tr = __shfl(T, (lane & 48) + ((lane >> 2) & 12) + r);
    float mr = __shfl(m, (lane & 48) + ((lane >> 2) & 12) + r);
    if (ln15 == 0) {
      float* stt = statB + row * 6;
      stt[0] = mr; stt[1] = Tr; stt[2] = Z; stt[3] = Tm; stt[4] = Th;
    }
  }
}

// ------- merge halves + per-block stat partials (reduce1 folded in) -------
__global__ __launch_bounds__(256) void merge_kernel(
    const __bf16* __restrict__ msgn0, const __bf16* __restrict__ msgn1,
    const float* __restrict__ statP, const unsigned char* __restrict__ mask8,
    __bf16* __restrict__ MSG16, float* __restrict__ partial) {
  __shared__ float sh3[12];
  int w = threadIdx.x >> 6;
  int row = blockIdx.x * 4 + w;
  int lane = threadIdx.x & 63;
  const float* s0 = statP + (size_t)row * 6;
  const float* s1 = statP + (size_t)(MTOK + row) * 6;
  float m0 = s0[0], T0 = s0[1], Z0 = s0[2], Tm0 = s0[3], Th0 = s0[4];
  float m1 = s1[0], T1 = s1[1], Z1 = s1[2], Tm1 = s1[3], Th1 = s1[4];
  int valid = mask8[row] != 0;
  float mm = fmaxf(m0, m1);
  float c0 = __expf(m0 - mm), c1 = __expf(m1 - mm);
  float w0 = c0 * Z0, w1 = c1 * Z1;
  float Z = w0 + w1;
  int ok = valid && (Z > 0.f);
  float invZ = ok ? (1.0f / Z) : 0.0f;
  float rw0 = w0 * invZ, rw1 = w1 * invZ;
  bf16x4 p0 = *(const bf16x4*)(msgn0 + (size_t)row * 256 + lane * 4);
  bf16x4 p1 = *(const bf16x4*)(msgn1 + (size_t)row * 256 + lane * 4);
  bf16x4 o;
#pragma unroll
  for (int q = 0; q < 4; ++q)
    o[q] = (__bf16)(rw0 * (float)p0[q] + rw1 * (float)p1[q]);
  *(bf16x4*)&MSG16[(size_t)row * 256 + lane * 4] = o;
  if (lane == 0) {
    float T = c0 * T0 + c1 * T1;
    float Tm = c0 * Tm0 + c1 * Tm1;
    float Th = c0 * Th0 + c1 * Th1;
    sh3[w * 3 + 0] = ok ? (__logf(Z) + mm - T * invZ) : 0.0f;
    sh3[w * 3 + 1] = ok ? (Tm * invZ) : 0.0f;
    sh3[w * 3 + 2] = ok ? (Th * invZ) : 0.0f;
  }
  __syncthreads();
  if (threadIdx.x == 0) {
    partial[blockIdx.x * 4 + 0] = sh3[0] + sh3[3] + sh3[6] + sh3[9];
    partial[blockIdx.x * 4 + 1] = sh3[1] + sh3[4] + sh3[7] + sh3[10];
    partial[blockIdx.x * 4 + 2] = sh3[2] + sh3[5] + sh3[8] + sh3[11];
  }
}

// ---------------- MFMA GEMM (gate / out), tile 128x64 (R12-validated) ------
template <int K, int MODE>
__global__ __launch_bounds__(256) void gemmb_kernel(
    const __bf16* __restrict__ A0, const __bf16* __restrict__ A1,
    const __bf16* __restrict__ WT, const float* __restrict__ bias,
    const float* __restrict__ xf, const __bf16* __restrict__ msg16,
    void* __restrict__ dst0) {
  __shared__ __align__(16) unsigned char As[128 * 128];
  __shared__ __align__(16) unsigned char Bs[64 * 128];
  int tid = threadIdx.x;
  int w = tid >> 6, lane = tid & 63, ln15 = lane & 15, lq = lane >> 4;
  int wr = w >> 1, wc = w & 1;
  int row0 = blockIdx.y * 128, col0 = blockIdx.x * 64;
  f32x4 acc[4][2];
#pragma unroll
  for (int i = 0; i < 4; ++i)
#pragma unroll
    for (int j = 0; j < 2; ++j) acc[i][j] = (f32x4){0.f, 0.f, 0.f, 0.f};

  int lr = lane >> 3;
  int sb = ((lane & 7) * 16) ^ ((lr & 7) << 4);

  for (int kt = 0; kt < K / 64; ++kt) {
    const __bf16* Ab = A0;
    int ktl = kt;
    if (K == 512 && kt >= 4) { Ab = A1; ktl = kt - 4; }
    __syncthreads();
#pragma unroll
    for (int i2 = 0; i2 < 4; ++i2) {
      int idx = w * 4 + i2;
      int grow = row0 + idx * 8 + lr;
      gl_lds16((const unsigned char*)Ab + (size_t)grow * 512 + ktl * 128 + sb,
               As + idx * 1024);
    }
#pragma unroll
    for (int i2 = 0; i2 < 2; ++i2) {
      int idx = w * 2 + i2;
      int gcol = col0 + idx * 8 + lr;
      gl_lds16((const unsigned char*)WT + (size_t)gcol * (K * 2) + kt * 128 + sb,
               Bs + idx * 1024);
    }
    __syncthreads();
#pragma unroll
    for (int ks = 0; ks < 2; ++ks) {
      bf16x8 af[4], bfr[2];
#pragma unroll
      for (int i = 0; i < 4; ++i) {
        int rl = wr * 64 + i * 16 + ln15;
        int byteoff = (lq * 16 + ks * 64) ^ ((rl & 7) << 4);
        af[i] = *(const bf16x8*)(As + rl * 128 + byteoff);
      }
#pragma unroll
      for (int j = 0; j < 2; ++j) {
        int cl = wc * 32 + j * 16 + ln15;
        int byteoff = (lq * 16 + ks * 64) ^ ((cl & 7) << 4);
        bfr[j] = *(const bf16x8*)(Bs + cl * 128 + byteoff);
      }
#pragma unroll
      for (int i = 0; i < 4; ++i)
#pragma unroll
        for (int j = 0; j < 2; ++j) acc[i][j] = MFMA16(af[i], bfr[j], acc[i][j]);
    }
  }
  float bj[2];
#pragma unroll
  for (int j = 0; j < 2; ++j) bj[j] = bias[col0 + wc * 32 + j * 16 + ln15];
#pragma unroll
  for (int i = 0; i < 4; ++i) {
#pragma unroll
    for (int ri = 0; ri < 4; ++ri) {
      int grow = row0 + wr * 64 + i * 16 + lq * 4 + ri;
#pragma unroll
      for (int j = 0; j < 2; ++j) {
        int gcol = col0 + wc * 32 + j * 16 + ln15;
        float o = acc[i][j][ri] + bj[j];
        if (MODE == 4) {
          float sg = 1.0f / (1.0f + __expf(-o));
          float mv = (float)msg16[(size_t)grow * 256 + gcol];
          ((__bf16*)dst0)[(size_t)grow * 256 + gcol] = (__bf16)(sg * mv);
        } else {
          ((float*)dst0)[(size_t)grow * 256 + gcol] =
              o + xf[(size_t)grow * 256 + gcol];
        }
      }
    }
  }
}

// ---------------- final reduction (4096 partials + col counts) ----------------
__device__ __forceinline__ float block_sum(float v, float* sh) {
  __syncthreads();
  sh[threadIdx.x] = v;
  __syncthreads();
  for (int s = 128; s > 0; s >>= 1) {
    if ((int)threadIdx.x < s) sh[threadIdx.x] += sh[threadIdx.x + s];
    __syncthreads();
  }
  return sh[0];
}

__global__ __launch_bounds__(256) void reduce2_kernel(
    const float* __restrict__ partial, const float* __restrict__ monf,
    const float* __restrict__ hubf, float* __restrict__ out3) {
  __shared__ float sh[256];
  float es = 0.f, ms = 0.f, hs = 0.f, cmf = 0.f, chf = 0.f;
  for (int i = threadIdx.x; i < 4096; i += 256) {
    es += partial[i * 4 + 0];
    ms += partial[i * 4 + 1];
    hs += partial[i * 4 + 2];
  }
  for (int j = threadIdx.x; j < NN; j += 256) { cmf += monf[j]; chf += hubf[j]; }
  float esum = block_sum(es, sh);
  float msum = block_sum(ms, sh);
  float hsum = block_sum(hs, sh);
  float cmsum = block_sum(cmf, sh);
  float chsum = block_sum(chf, sh);
  if (threadIdx.x == 0) {
    out3[0] = esum / 16384.0f;
    out3[1] = (cmsum > 0.f) ? (msum / (cmsum * 16384.0f)) : 0.0f;
    out3[2] = (chsum > 0.f) ? (hsum / (chsum * 16384.0f)) : 0.0f;
  }
}

extern "C" void kernel_launch(void* const* d_in, const int* in_sizes, int n_in,
                              void* d_out, int out_size, void* d_ws, size_t ws_size,
                              hipStream_t stream) {
  const float* x = (const float*)d_in[0];
  const int* roles = (const int*)d_in[1];
  const void* mraw = d_in[2];
  const float* gamma = (const float*)d_in[3];
  const float* beta = (const float*)d_in[4];
  const float* remb = (const float*)d_in[5];
  const float* Wq = (const float*)d_in[6];
  const float* bq = (const float*)d_in[7];
  const float* Wk = (const float*)d_in[8];
  const float* bk = (const float*)d_in[9];
  const float* Ws = (const float*)d_in[10];
  const float* bs = (const float*)d_in[11];
  const float* Wp = (const float*)d_in[12];
  const float* bp = (const float*)d_in[13];
  const float* Wo = (const float*)d_in[14];
  const float* bo = (const float*)d_in[15];
  const float* Wg = (const float*)d_in[16];
  const float* bg = (const float*)d_in[17];

  float* ws = (float*)d_ws;
  __bf16* X16 = (__bf16*)(ws + OFF_X16);
  __bf16* N16 = (__bf16*)(ws + OFF_N16);
  __bf16* H16 = (__bf16*)(ws + OFF_H16);
  __bf16* Grow = (__bf16*)(ws + OFF_GROW);
  __bf16* Gcol = (__bf16*)(ws + OFF_GCOL);
  __bf16* PTE = (__bf16*)(ws + OFF_PTE);
  __bf16* WT = (__bf16*)(ws + OFF_WT);
  float* statP = ws + OFF_STAT;
  __bf16* msgn0 = (__bf16*)(ws + OFF_MSGN0);
  __bf16* msgn1 = (__bf16*)(ws + OFF_MSGN1);
  float* partial = ws + OFF_PARTM;
  __bf16* MSG16 = (__bf16*)(ws + OFF_MSG16);
  __bf16* GM16 = (__bf16*)(ws + OFF_GM16);
  float* monfp = ws + OFF_MONF;
  float* hubfp = ws + OFF_HUBF;
  unsigned char* mask8 = (unsigned char*)(ws + OFF_MASK);
  float* out = (float*)d_out;

  __bf16* WTg = WT + 262144;
  __bf16* WTo = WT + 393216;

  setup_kernel<<<4416, 256, 0, stream>>>(x, roles, mraw, gamma, beta, remb,
                                         Wq, Wk, Ws, Wp, Wg, Wo,
                                         X16, N16, H16, WT, mask8, monfp,
                                         hubfp, PTE);
  proj4_kernel<<<dim3(2, 128, 4), 256, 0, stream>>>(
      H16, N16, WT, bq, bk, bs, bp, roles, remb, Grow, Gcol, PTE);
  attn_kernel<<<512, 256, 0, stream>>>(Grow, Gcol, PTE, mask8, msgn0, msgn1,
                                       statP);
  merge_kernel<<<4096, 256, 0, stream>>>(msgn0, msgn1, statP, mask8, MSG16,
                                         partial);
  dim3 gg(4, 128);
  gemmb_kernel<512, 4><<<gg, 256, 0, stream>>>(X16, MSG16, WTg, bg, nullptr,
                                               MSG16, GM16);
  gemmb_kernel<256, 5><<<gg, 256, 0, stream>>>(GM16, nullptr, WTo, bo, x,
                                               nullptr, out);
  reduce2_kernel<<<1, 256, 0, stream>>>(partial, monfp, hubfp, out + 4194304);
}